// Round 8
// baseline (801.152 us; speedup 1.0000x reference)
//
#include <hip/hip_runtime.h>
#include <math.h>

#define HW 65536
#define NPOS 262144   // B*HW

typedef __attribute__((ext_vector_type(8))) short short8;
typedef __attribute__((ext_vector_type(4))) float float4v;

__device__ __forceinline__ float gelu_exact(float v){
    return 0.5f * v * (1.0f + erff(v * 0.70710678118654752f));
}
__device__ __forceinline__ float sigmoid_(float v){
    return 1.0f / (1.0f + __expf(-v));
}
__device__ __forceinline__ unsigned short f2bf(float f){
    unsigned u = __builtin_bit_cast(unsigned, f);
    unsigned r = (u + 0x7fffu + ((u >> 16) & 1u)) >> 16;
    return (unsigned short)r;
}
__device__ __forceinline__ float bf2f(unsigned short h){
    unsigned u = ((unsigned)h) << 16;
    return __builtin_bit_cast(float, u);
}

// ---------------------------------------------------------------------------
// K0: weight prep.
//  gid < 147456: 4 SFM 3x3 weights [oc][ic][9] fp32 -> [w][tap][oc][ic] bf16
//  gid >= 147456: wkv/wq 1x1 weights fp32 -> hi/lo bf16 [192 rows][64 ic]
// ---------------------------------------------------------------------------
__global__ __launch_bounds__(256) void k_wprep(
    const float* __restrict__ w0, const float* __restrict__ w1,
    const float* __restrict__ w2, const float* __restrict__ w3,
    const float* __restrict__ wkv, const float* __restrict__ wq,
    unsigned short* __restrict__ dst,
    unsigned short* __restrict__ whi, unsigned short* __restrict__ wlo)
{
    int gid = blockIdx.x * 256 + threadIdx.x;
    if (gid < 147456){
        int w = gid / 36864;
        int rem = gid - w * 36864;
        int t = rem >> 12;            // tap
        int oi = rem & 4095;
        int oc = oi >> 6, ic = oi & 63;
        const float* src = (w == 0) ? w0 : (w == 1) ? w1 : (w == 2) ? w2 : w3;
        dst[gid] = f2bf(src[oc*576 + ic*9 + t]);
    } else {
        int e = gid - 147456;         // < 12288
        int row = e >> 6;
        float f = (row < 128) ? wkv[e] : wq[e - 8192];
        unsigned short h = f2bf(f);
        whi[e] = h;
        wlo[e] = f2bf(f - bf2f(h));
    }
}

// ---------------------------------------------------------------------------
// K1: LN1(ref) -> 1x1 w_kv (k_pre,v_pre) ; LN3(x) -> 1x1 w_q (q_pre)
// MFMA version, hi/lo bf16 split for fp32-class precision. W fragments
// direct from global; LDS = X buffers only -> 2 blocks/CU. (R5 verified.)
// ---------------------------------------------------------------------------
__global__ __launch_bounds__(256, 2) void k_ln_1x1_mfma(
    const float* __restrict__ x, const float* __restrict__ ref,
    const float* __restrict__ ln1w, const float* __restrict__ ln1b,
    const float* __restrict__ ln3w, const float* __restrict__ ln3b,
    const unsigned short* __restrict__ whi, const unsigned short* __restrict__ wlo,
    float* __restrict__ kpre, float* __restrict__ vpre, float* __restrict__ qpre,
    float* __restrict__ zbuf)
{
    __shared__ unsigned short Xhi[256*72];   // 36864 B
    __shared__ unsigned short Xlo[256*72];   // 36864 B
    __shared__ float s_ln[4][64];            // ln1w, ln1b, ln3w, ln3b

    int t = threadIdx.x;
    int b = blockIdx.x >> 8;                 // 4 batches x 256 tiles
    int pos0 = (blockIdx.x & 255) << 8;

    if (blockIdx.x == 0){
        for (int j = t; j < 4608; j += 256) zbuf[j] = 0.f;
    }
    if (t < 64){
        s_ln[0][t] = ln1w[t]; s_ln[1][t] = ln1b[t];
        s_ln[2][t] = ln3w[t]; s_ln[3][t] = ln3b[t];
    }

    int pos = pos0 + t;
    const size_t base = (size_t)b * 64 * HW + pos;
    int wave = t >> 6, lane = t & 63;
    int q = lane >> 4, l = lane & 15;
    int pb = wave * 64;

    // ---- P1: LN1(ref) -> Xhi/Xlo ----
    {
        float v[64];
        float s = 0.f, ss = 0.f;
        #pragma unroll
        for (int c = 0; c < 64; c++){ float r = ref[base + (size_t)c*HW]; v[c] = r; s += r; ss += r*r; }
        float mu  = s * (1.0f/64.0f);
        float var = ss * (1.0f/64.0f) - mu*mu;
        float inv = rsqrtf(var + 1e-5f);
        __syncthreads();   // s_ln visible
        #pragma unroll
        for (int c0 = 0; c0 < 64; c0 += 8){
            unsigned short h8[8], l8[8];
            #pragma unroll
            for (int i = 0; i < 8; i++){
                float f = (v[c0+i]-mu)*inv*s_ln[0][c0+i] + s_ln[1][c0+i];
                unsigned short h = f2bf(f);
                h8[i] = h; l8[i] = f2bf(f - bf2f(h));
            }
            *(short8*)(&Xhi[t*72 + c0]) = *(short8*)h8;
            *(short8*)(&Xlo[t*72 + c0]) = *(short8*)l8;
        }
    }
    __syncthreads();

    // ---- P2: kv GEMM: 128 oc x 64 px per wave ----
    {
        float4v acc[8][4];
        #pragma unroll
        for (int m = 0; m < 8; m++)
            #pragma unroll
            for (int n = 0; n < 4; n++) acc[m][n] = (float4v){0.f,0.f,0.f,0.f};
        #pragma unroll
        for (int c = 0; c < 2; c++){
            short8 ah[8], al[8];
            #pragma unroll
            for (int m = 0; m < 8; m++){
                ah[m] = *(const short8*)(whi + (m*16 + l)*64 + c*32 + q*8);
                al[m] = *(const short8*)(wlo + (m*16 + l)*64 + c*32 + q*8);
            }
            #pragma unroll
            for (int n = 0; n < 4; n++){
                short8 bh = *(const short8*)(&Xhi[(pb + n*16 + l)*72 + c*32 + q*8]);
                short8 bl = *(const short8*)(&Xlo[(pb + n*16 + l)*72 + c*32 + q*8]);
                #pragma unroll
                for (int m = 0; m < 8; m++){
                    acc[m][n] = __builtin_amdgcn_mfma_f32_16x16x32_bf16(ah[m], bh, acc[m][n], 0, 0, 0);
                    acc[m][n] = __builtin_amdgcn_mfma_f32_16x16x32_bf16(ah[m], bl, acc[m][n], 0, 0, 0);
                    acc[m][n] = __builtin_amdgcn_mfma_f32_16x16x32_bf16(al[m], bh, acc[m][n], 0, 0, 0);
                }
            }
        }
        #pragma unroll
        for (int m = 0; m < 8; m++){
            #pragma unroll
            for (int n = 0; n < 4; n++){
                int px = pos0 + pb + n*16 + l;
                #pragma unroll
                for (int i = 0; i < 4; i++){
                    int oc = m*16 + q*4 + i;
                    float val = acc[m][n][i];
                    if (m < 4) kpre[(size_t)(b*64 + oc)*HW + px] = val;
                    else       vpre[(size_t)(b*64 + (oc-64))*HW + px] = val;
                }
            }
        }
    }
    __syncthreads();

    // ---- P3: LN3(x) -> Xhi/Xlo ----
    {
        float v[64];
        float s = 0.f, ss = 0.f;
        #pragma unroll
        for (int c = 0; c < 64; c++){ float r = x[base + (size_t)c*HW]; v[c] = r; s += r; ss += r*r; }
        float mu  = s * (1.0f/64.0f);
        float var = ss * (1.0f/64.0f) - mu*mu;
        float inv = rsqrtf(var + 1e-5f);
        #pragma unroll
        for (int c0 = 0; c0 < 64; c0 += 8){
            unsigned short h8[8], l8[8];
            #pragma unroll
            for (int i = 0; i < 8; i++){
                float f = (v[c0+i]-mu)*inv*s_ln[2][c0+i] + s_ln[3][c0+i];
                unsigned short h = f2bf(f);
                h8[i] = h; l8[i] = f2bf(f - bf2f(h));
            }
            *(short8*)(&Xhi[t*72 + c0]) = *(short8*)h8;
            *(short8*)(&Xlo[t*72 + c0]) = *(short8*)l8;
        }
    }
    __syncthreads();

    // ---- P4: q GEMM: 64 oc x 64 px per wave (weight rows 128..191) ----
    {
        float4v acc[4][4];
        #pragma unroll
        for (int m = 0; m < 4; m++)
            #pragma unroll
            for (int n = 0; n < 4; n++) acc[m][n] = (float4v){0.f,0.f,0.f,0.f};
        #pragma unroll
        for (int c = 0; c < 2; c++){
            short8 ah[4], al[4];
            #pragma unroll
            for (int m = 0; m < 4; m++){
                ah[m] = *(const short8*)(whi + (128 + m*16 + l)*64 + c*32 + q*8);
                al[m] = *(const short8*)(wlo + (128 + m*16 + l)*64 + c*32 + q*8);
            }
            #pragma unroll
            for (int n = 0; n < 4; n++){
                short8 bh = *(const short8*)(&Xhi[(pb + n*16 + l)*72 + c*32 + q*8]);
                short8 bl = *(const short8*)(&Xlo[(pb + n*16 + l)*72 + c*32 + q*8]);
                #pragma unroll
                for (int m = 0; m < 4; m++){
                    acc[m][n] = __builtin_amdgcn_mfma_f32_16x16x32_bf16(ah[m], bh, acc[m][n], 0, 0, 0);
                    acc[m][n] = __builtin_amdgcn_mfma_f32_16x16x32_bf16(ah[m], bl, acc[m][n], 0, 0, 0);
                    acc[m][n] = __builtin_amdgcn_mfma_f32_16x16x32_bf16(al[m], bh, acc[m][n], 0, 0, 0);
                }
            }
        }
        #pragma unroll
        for (int m = 0; m < 4; m++){
            #pragma unroll
            for (int n = 0; n < 4; n++){
                int px = pos0 + pb + n*16 + l;
                #pragma unroll
                for (int i = 0; i < 4; i++){
                    int oc = m*16 + q*4 + i;
                    qpre[(size_t)(b*64 + oc)*HW + px] = acc[m][n][i];
                }
            }
        }
    }
}

// ---------------------------------------------------------------------------
// K2: depthwise 3x3, pad 1 (fp32 NCHW). Vectorized: 128-px tiles, each
// thread computes 4 px with float4 store.
// ---------------------------------------------------------------------------
__global__ __launch_bounds__(256) void k_dw3x3(
    const float* __restrict__ in, const float* __restrict__ w9,
    float* __restrict__ out)
{
    __shared__ float s_in[10*132];
    int t  = threadIdx.x;
    int b  = blockIdx.z >> 6, ch = blockIdx.z & 63;
    int x0 = blockIdx.x * 128, y0 = blockIdx.y * 8;
    const float* src = in + (size_t)(b*64+ch)*HW;
    for (int j = t; j < 1300; j += 256){
        int r = j / 130, cc = j - r*130;
        int gy = y0 - 1 + r, gx = x0 - 1 + cc;
        float val = 0.f;
        if (gy >= 0 && gy < 256 && gx >= 0 && gx < 256) val = src[gy*256 + gx];
        s_in[r*132 + cc] = val;
    }
    float w[9];
    #pragma unroll
    for (int k = 0; k < 9; k++) w[k] = w9[ch*9 + k];
    __syncthreads();
    int ty = t >> 5, tx4 = (t & 31) << 2;
    float o[4] = {0.f, 0.f, 0.f, 0.f};
    #pragma unroll
    for (int ky = 0; ky < 3; ky++){
        float f[6];
        #pragma unroll
        for (int i = 0; i < 6; i++) f[i] = s_in[(ty+ky)*132 + tx4 + i];
        #pragma unroll
        for (int px = 0; px < 4; px++){
            o[px] += w[ky*3+0] * f[px];
            o[px] += w[ky*3+1] * f[px+1];
            o[px] += w[ky*3+2] * f[px+2];
        }
    }
    *(float4v*)(&out[(size_t)(b*64+ch)*HW + (y0+ty)*256 + x0 + tx4]) = *(float4v*)o;
}

// ---------------------------------------------------------------------------
// K3: q.kT dots via MFMA (hi/lo bf16 3-term) + fused per-channel sum-sq.
// No LDS; frags straight from global. (R7 verified.)
// ---------------------------------------------------------------------------
__global__ __launch_bounds__(256) void k_qk_mfma(
    const float* __restrict__ q, const float* __restrict__ k,
    float* __restrict__ dots, float* __restrict__ sqq, float* __restrict__ sqk)
{
    int t = threadIdx.x;
    int b = blockIdx.x >> 8;
    int p0 = (blockIdx.x & 255) * 256;
    int wave = t >> 6, lane = t & 63;
    int h = wave;
    int row = lane & 15, kg = lane >> 4;

    const float* qrow = q + (size_t)(b*64 + h*16 + row)*HW;
    const float* krow = k + (size_t)(b*64 + h*16 + row)*HW;

    float4v acc = (float4v){0.f, 0.f, 0.f, 0.f};
    float sq = 0.f, sk = 0.f;

    for (int step = 0; step < 8; step++){
        int p = p0 + step*32 + kg*8;
        float qa[8], ka[8];
        #pragma unroll
        for (int j = 0; j < 8; j++){ qa[j] = qrow[p+j]; ka[j] = krow[p+j]; }
        unsigned short qh8[8], ql8[8], kh8[8], kl8[8];
        #pragma unroll
        for (int j = 0; j < 8; j++){
            sq += qa[j]*qa[j];
            sk += ka[j]*ka[j];
            unsigned short hh = f2bf(qa[j]);
            qh8[j] = hh; ql8[j] = f2bf(qa[j] - bf2f(hh));
            hh = f2bf(ka[j]);
            kh8[j] = hh; kl8[j] = f2bf(ka[j] - bf2f(hh));
        }
        short8 ah = *(short8*)qh8, al = *(short8*)ql8;
        short8 bh = *(short8*)kh8, bl = *(short8*)kl8;
        acc = __builtin_amdgcn_mfma_f32_16x16x32_bf16(ah, bh, acc, 0, 0, 0);
        acc = __builtin_amdgcn_mfma_f32_16x16x32_bf16(ah, bl, acc, 0, 0, 0);
        acc = __builtin_amdgcn_mfma_f32_16x16x32_bf16(al, bh, acc, 0, 0, 0);
    }

    // sum-sq reduce across kg groups (lanes row, row+16, row+32, row+48)
    sq += __shfl_xor(sq, 16); sq += __shfl_xor(sq, 32);
    sk += __shfl_xor(sk, 16); sk += __shfl_xor(sk, 32);
    if (lane < 16){
        atomicAdd(&sqq[b*64 + h*16 + row], sq);
        atomicAdd(&sqk[b*64 + h*16 + row], sk);
    }
    // C layout: cq = kg*4 + i, cd = row
    int dbase = ((b*4 + h)*16 + kg*4)*16 + row;
    atomicAdd(&dots[dbase + 0*16], acc[0]);
    atomicAdd(&dots[dbase + 1*16], acc[1]);
    atomicAdd(&dots[dbase + 2*16], acc[2]);
    atomicAdd(&dots[dbase + 3*16], acc[3]);
}

// ---------------------------------------------------------------------------
// K4: normalize + temperature + softmax over d, then fold the projection:
// M_b = Wproj @ blockdiag(A_b)  ->  x1 = x + M_b . v  (single GEMM later).
// ---------------------------------------------------------------------------
__global__ __launch_bounds__(256) void k_softmax_m(
    const float* __restrict__ dots, const float* __restrict__ sqq,
    const float* __restrict__ sqk, const float* __restrict__ temp,
    const float* __restrict__ wproj,
    unsigned short* __restrict__ Mhi, unsigned short* __restrict__ Mlo)
{
    __shared__ float s_wp[4096];
    __shared__ float s_at[1024];
    int t = threadIdx.x;
    int b = blockIdx.x;

    for (int j = t; j < 4096; j += 256) s_wp[j] = wproj[j];

    if (t < 64){
        int h = t >> 4, cq = t & 15;
        float nq = fmaxf(sqrtf(sqq[b*64 + h*16 + cq]), 1e-12f);
        float tp = temp[h];
        float l[16];
        float m = -1e30f;
        #pragma unroll
        for (int d = 0; d < 16; d++){
            float nk = fmaxf(sqrtf(sqk[b*64 + h*16 + d]), 1e-12f);
            float v = dots[((b*4+h)*16 + cq)*16 + d] / (nq*nk) * tp;
            l[d] = v; m = fmaxf(m, v);
        }
        float s = 0.f;
        #pragma unroll
        for (int d = 0; d < 16; d++){ l[d] = __expf(l[d]-m); s += l[d]; }
        float invs = 1.0f / s;
        #pragma unroll
        for (int d = 0; d < 16; d++) s_at[(h*16 + cq)*16 + d] = l[d]*invs;
    }
    __syncthreads();

    // M: 4096 entries, 16 each
    for (int e = t; e < 4096; e += 256){
        int c = e >> 6, kk = e & 63;
        int h = kk >> 4, d = kk & 15;
        float a = 0.f;
        #pragma unroll
        for (int r = 0; r < 16; r++)
            a += s_wp[c*64 + h*16 + r] * s_at[(h*16 + r)*16 + d];
        unsigned short hh = f2bf(a);
        Mhi[b*4096 + e] = hh;
        Mlo[b*4096 + e] = f2bf(a - bf2f(hh));
    }
}

// ---------------------------------------------------------------------------
// K5: x1 = x + M_b.v  (MFMA, hi/lo bf16 3-term) ; y = LN2(x1).
// Emit x1 and y as bf16 NHWC [b][y][x][c] for the MFMA SFM convs.
// ---------------------------------------------------------------------------
__global__ __launch_bounds__(256, 2) void k_attnv_mfma(
    const float* __restrict__ v, const float* __restrict__ x,
    const unsigned short* __restrict__ Mhi_g, const unsigned short* __restrict__ Mlo_g,
    const float* __restrict__ ln2w, const float* __restrict__ ln2b,
    unsigned short* __restrict__ x1_bf, unsigned short* __restrict__ y_bf)
{
    __shared__ unsigned short Mhi[64*72];    // 9216 B
    __shared__ unsigned short Mlo[64*72];    // 9216 B
    __shared__ float s_lw[64], s_lb[64];
    int t = threadIdx.x;
    int b = blockIdx.x >> 8;
    int pos0 = (blockIdx.x & 255) << 8;

    for (int e = t; e < 4096; e += 256){
        int row = e >> 6, ic = e & 63;
        Mhi[row*72 + ic] = Mhi_g[b*4096 + e];
        Mlo[row*72 + ic] = Mlo_g[b*4096 + e];
    }
    if (t < 64){ s_lw[t] = ln2w[t]; s_lb[t] = ln2b[t]; }
    __syncthreads();

    int wave = t >> 6, lane = t & 63;
    int q = lane >> 4, l = lane & 15;
    int px0 = pos0 + wave*64;                // wave's 64-px slab

    float4v acc[4][4];
    #pragma unroll
    for (int m = 0; m < 4; m++)
        #pragma unroll
        for (int n = 0; n < 4; n++) acc[m][n] = (float4v){0.f,0.f,0.f,0.f};

    #pragma unroll
    for (int c = 0; c < 2; c++){
        short8 ah[4], al[4];
        #pragma unroll
        for (int m = 0; m < 4; m++){
            ah[m] = *(const short8*)(&Mhi[(m*16 + l)*72 + c*32 + q*8]);
            al[m] = *(const short8*)(&Mlo[(m*16 + l)*72 + c*32 + q*8]);
        }
        #pragma unroll
        for (int n = 0; n < 4; n++){
            float vv[8];
            #pragma unroll
            for (int j = 0; j < 8; j++)
                vv[j] = v[(size_t)(b*64 + c*32 + q*8 + j)*HW + px0 + n*16 + l];
            unsigned short bh8[8], bl8[8];
            #pragma unroll
            for (int j = 0; j < 8; j++){
                unsigned short h = f2bf(vv[j]);
                bh8[j] = h; bl8[j] = f2bf(vv[j] - bf2f(h));
            }
            short8 bh = *(short8*)bh8, bl = *(short8*)bl8;
            #pragma unroll
            for (int m = 0; m < 4; m++){
                acc[m][n] = __builtin_amdgcn_mfma_f32_16x16x32_bf16(ah[m], bh, acc[m][n], 0, 0, 0);
                acc[m][n] = __builtin_amdgcn_mfma_f32_16x16x32_bf16(ah[m], bl, acc[m][n], 0, 0, 0);
                acc[m][n] = __builtin_amdgcn_mfma_f32_16x16x32_bf16(al[m], bh, acc[m][n], 0, 0, 0);
            }
        }
    }

    // epilogue: per n-tile -> x-add, LN2 stats via shfl over q, pack bf16
    #pragma unroll
    for (int n = 0; n < 4; n++){
        int px = px0 + n*16 + l;
        float val[4][4];
        float sn = 0.f, ssn = 0.f;
        #pragma unroll
        for (int m = 0; m < 4; m++){
            #pragma unroll
            for (int i = 0; i < 4; i++){
                float f = acc[m][n][i] + x[(size_t)(b*64 + m*16 + q*4 + i)*HW + px];
                val[m][i] = f; sn += f; ssn += f*f;
            }
        }
        sn  += __shfl_xor(sn, 16);  sn  += __shfl_xor(sn, 32);
        ssn += __shfl_xor(ssn, 16); ssn += __shfl_xor(ssn, 32);
        float mu  = sn * (1.0f/64.0f);
        float var = ssn * (1.0f/64.0f) - mu*mu;
        float inv = rsqrtf(var + 1e-5f);
        size_t nb = ((size_t)b*HW + px) * 64;
        #pragma unroll
        for (int m = 0; m < 4; m++){
            int ocb = m*16 + q*4;
            unsigned short xv[4], yv[4];
            #pragma unroll
            for (int i = 0; i < 4; i++){
                float f = val[m][i];
                xv[i] = f2bf(f);
                yv[i] = f2bf((f - mu) * inv * s_lw[ocb+i] + s_lb[ocb+i]);
            }
            *(unsigned long long*)(x1_bf + nb + ocb) = *(unsigned long long*)xv;
            *(unsigned long long*)(y_bf  + nb + ocb) = *(unsigned long long*)yv;
        }
    }
}

// ---------------------------------------------------------------------------
// K6a: fused dual 3x3 conv over y: t1 = gelu(conv(y,wA)), t2 = gelu(conv(y,wB)).
// One X staging feeds both weight sets (2x MFMA per staged byte). Weight
// fragments direct from global (L2-resident, lane-varying 16B loads) -> no
// Ws LDS, no per-tap barriers.
// ---------------------------------------------------------------------------
__global__ __launch_bounds__(256, 2) void k_conv_dual(
    const unsigned short* __restrict__ in,
    const unsigned short* __restrict__ wtA,
    const unsigned short* __restrict__ wtB,
    unsigned short* __restrict__ o1,
    unsigned short* __restrict__ o2)
{
    __shared__ unsigned short Xs[4*130*40];   // 41600 B
    int tid  = threadIdx.x;
    int b    = blockIdx.z;
    int y0   = blockIdx.y * 2;
    int x0   = blockIdx.x * 128;
    int wave = tid >> 6, lane = tid & 63;
    int q = lane >> 4, l = lane & 15;
    int r = wave >> 1;
    int pb = (wave & 1) * 64;

    float4v accA[4][4], accB[4][4];
    #pragma unroll
    for (int m = 0; m < 4; m++)
        #pragma unroll
        for (int n = 0; n < 4; n++){
            accA[m][n] = (float4v){0.f,0.f,0.f,0.f};
            accB[m][n] = (float4v){0.f,0.f,0.f,0.f};
        }

    for (int c = 0; c < 2; ++c){
        __syncthreads();
        for (int j = tid; j < 2080; j += 256){
            int row = j / 520;
            int rem = j - row*520;
            int px  = rem >> 2;
            int part= rem & 3;
            int gy = y0 - 1 + row, gx = x0 - 1 + px;
            short8 v = (short8)0;
            if (gy >= 0 && gy < 256 && gx >= 0 && gx < 256){
                v = *(const short8*)(in + (((size_t)b*HW + gy*256 + gx) * 64) + c*32 + part*8);
            }
            *(short8*)(&Xs[(row*130 + px)*40 + part*8]) = v;
        }
        __syncthreads();
        for (int t = 0; t < 9; ++t){
            int ky = t / 3, kx = t - ky*3;
            short8 afrA[4], afrB[4];
            #pragma unroll
            for (int m = 0; m < 4; m++){
                afrA[m] = *(const short8*)(wtA + ((size_t)(t*64 + m*16 + l))*64 + c*32 + q*8);
                afrB[m] = *(const short8*)(wtB + ((size_t)(t*64 + m*16 + l))*64 + c*32 + q*8);
            }
            #pragma unroll
            for (int n = 0; n < 4; n++){
                int px = pb + n*16 + l;
                short8 bfr = *(const short8*)(&Xs[((r+ky)*130 + px + kx)*40 + q*8]);
                #pragma unroll
                for (int m = 0; m < 4; m++){
                    accA[m][n] = __builtin_amdgcn_mfma_f32_16x16x32_bf16(afrA[m], bfr, accA[m][n], 0, 0, 0);
                    accB[m][n] = __builtin_amdgcn_mfma_f32_16x16x32_bf16(afrB[m], bfr, accB[m][n], 0, 0, 0);
                }
            }
        }
    }

    int gy = y0 + r;
    #pragma unroll
    for (int n = 0; n < 4; n++){
        int gx = x0 + pb + n*16 + l;
        size_t pixbase = ((size_t)b*HW + gy*256 + gx) * 64;
        #pragma unroll
        for (int m = 0; m < 4; m++){
            int ocb = m*16 + q*4;
            unsigned short p1[4], p2[4];
            #pragma unroll
            for (int i = 0; i < 4; i++){
                p1[i] = f2bf(gelu_exact(accA[m][n][i]));
                p2[i] = f2bf(gelu_exact(accB[m][n][i]));
            }
            *(unsigned long long*)(o1 + pixbase + ocb) = *(unsigned long long*)p1;
            *(unsigned long long*)(o2 + pixbase + ocb) = *(unsigned long long*)p2;
        }
    }
}

// ---------------------------------------------------------------------------
// K6b: fused z kernel: z = y * sigmoid(conv(t2,wB)) + conv(t1,wA).
// Per c-chunk: stage t1 chunk -> 9 taps -> accA; stage t2 chunk -> accB.
// xadd intermediate eliminated (64MB traffic); add uses fp32 accA directly.
// ---------------------------------------------------------------------------
__global__ __launch_bounds__(256, 2) void k_conv_zfuse(
    const unsigned short* __restrict__ in1,   // t1
    const unsigned short* __restrict__ in2,   // t2
    const unsigned short* __restrict__ wtA,   // wadd2
    const unsigned short* __restrict__ wtB,   // wmul1
    const unsigned short* __restrict__ yb,    // y_bf
    unsigned short* __restrict__ zo)
{
    __shared__ unsigned short Xs[4*130*40];   // 41600 B
    int tid  = threadIdx.x;
    int b    = blockIdx.z;
    int y0   = blockIdx.y * 2;
    int x0   = blockIdx.x * 128;
    int wave = tid >> 6, lane = tid & 63;
    int q = lane >> 4, l = lane & 15;
    int r = wave >> 1;
    int pb = (wave & 1) * 64;

    float4v accA[4][4], accB[4][4];
    #pragma unroll
    for (int m = 0; m < 4; m++)
        #pragma unroll
        for (int n = 0; n < 4; n++){
            accA[m][n] = (float4v){0.f,0.f,0.f,0.f};
            accB[m][n] = (float4v){0.f,0.f,0.f,0.f};
        }

    for (int c = 0; c < 2; ++c){
        #pragma unroll
        for (int pass = 0; pass < 2; ++pass){
            const unsigned short* src = (pass == 0) ? in1 : in2;
            const unsigned short* wt  = (pass == 0) ? wtA : wtB;
            __syncthreads();
            for (int j = tid; j < 2080; j += 256){
                int row = j / 520;
                int rem = j - row*520;
                int px  = rem >> 2;
                int part= rem & 3;
                int gy = y0 - 1 + row, gx = x0 - 1 + px;
                short8 v = (short8)0;
                if (gy >= 0 && gy < 256 && gx >= 0 && gx < 256){
                    v = *(const short8*)(src + (((size_t)b*HW + gy*256 + gx) * 64) + c*32 + part*8);
                }
                *(short8*)(&Xs[(row*130 + px)*40 + part*8]) = v;
            }
            __syncthreads();
            for (int t = 0; t < 9; ++t){
                int ky = t / 3, kx = t - ky*3;
                short8 afr[4];
                #pragma unroll
                for (int m = 0; m < 4; m++)
                    afr[m] = *(const short8*)(wt + ((size_t)(t*64 + m*16 + l))*64 + c*32 + q*8);
                #pragma unroll
                for (int n = 0; n < 4; n++){
                    int px = pb + n*16 + l;
                    short8 bfr = *(const short8*)(&Xs[((r+ky)*130 + px + kx)*40 + q*8]);
                    #pragma unroll
                    for (int m = 0; m < 4; m++){
                        if (pass == 0)
                            accA[m][n] = __builtin_amdgcn_mfma_f32_16x16x32_bf16(afr[m], bfr, accA[m][n], 0, 0, 0);
                        else
                            accB[m][n] = __builtin_amdgcn_mfma_f32_16x16x32_bf16(afr[m], bfr, accB[m][n], 0, 0, 0);
                    }
                }
            }
        }
    }

    int gy = y0 + r;
    #pragma unroll
    for (int n = 0; n < 4; n++){
        int gx = x0 + pb + n*16 + l;
        size_t pixbase = ((size_t)b*HW + gy*256 + gx) * 64;
        #pragma unroll
        for (int m = 0; m < 4; m++){
            int ocb = m*16 + q*4;
            unsigned long long yu = *(const unsigned long long*)(yb + pixbase + ocb);
            const unsigned short* y4 = (const unsigned short*)&yu;
            unsigned short pk[4];
            #pragma unroll
            for (int i = 0; i < 4; i++){
                float z = bf2f(y4[i]) * sigmoid_(accB[m][n][i]) + accA[m][n][i];
                pk[i] = f2bf(z);
            }
            *(unsigned long long*)(zo + pixbase + ocb) = *(unsigned long long*)pk;
        }
    }
}

// ---------------------------------------------------------------------------
// K6c: final conv: out = x1 + conv(z, wfuse)  (fp32 NCHW out).
// Weights direct from global (same recipe); LDS = X only.
// ---------------------------------------------------------------------------
__global__ __launch_bounds__(256, 2) void k_conv_final(
    const unsigned short* __restrict__ in,    // z_bf
    const unsigned short* __restrict__ wt,    // wfuse taps
    const unsigned short* __restrict__ x1,    // x1_bf
    float* __restrict__ outf)
{
    __shared__ unsigned short Xs[4*130*40];   // 41600 B
    int tid  = threadIdx.x;
    int b    = blockIdx.z;
    int y0   = blockIdx.y * 2;
    int x0   = blockIdx.x * 128;
    int wave = tid >> 6, lane = tid & 63;
    int q = lane >> 4, l = lane & 15;
    int r = wave >> 1;
    int pb = (wave & 1) * 64;

    float4v acc[4][4];
    #pragma unroll
    for (int m = 0; m < 4; m++)
        #pragma unroll
        for (int n = 0; n < 4; n++) acc[m][n] = (float4v){0.f,0.f,0.f,0.f};

    for (int c = 0; c < 2; ++c){
        __syncthreads();
        for (int j = tid; j < 2080; j += 256){
            int row = j / 520;
            int rem = j - row*520;
            int px  = rem >> 2;
            int part= rem & 3;
            int gy = y0 - 1 + row, gx = x0 - 1 + px;
            short8 v = (short8)0;
            if (gy >= 0 && gy < 256 && gx >= 0 && gx < 256){
                v = *(const short8*)(in + (((size_t)b*HW + gy*256 + gx) * 64) + c*32 + part*8);
            }
            *(short8*)(&Xs[(row*130 + px)*40 + part*8]) = v;
        }
        __syncthreads();
        for (int t = 0; t < 9; ++t){
            int ky = t / 3, kx = t - ky*3;
            short8 afr[4];
            #pragma unroll
            for (int m = 0; m < 4; m++)
                afr[m] = *(const short8*)(wt + ((size_t)(t*64 + m*16 + l))*64 + c*32 + q*8);
            #pragma unroll
            for (int n = 0; n < 4; n++){
                int px = pb + n*16 + l;
                short8 bfr = *(const short8*)(&Xs[((r+ky)*130 + px + kx)*40 + q*8]);
                #pragma unroll
                for (int m = 0; m < 4; m++)
                    acc[m][n] = __builtin_amdgcn_mfma_f32_16x16x32_bf16(afr[m], bfr, acc[m][n], 0, 0, 0);
            }
        }
    }

    int gy = y0 + r;
    #pragma unroll
    for (int n = 0; n < 4; n++){
        int gx = x0 + pb + n*16 + l;
        size_t pixbase = ((size_t)b*HW + gy*256 + gx) * 64;
        #pragma unroll
        for (int m = 0; m < 4; m++){
            int ocb = m*16 + q*4;
            unsigned long long xu = *(const unsigned long long*)(x1 + pixbase + ocb);
            const unsigned short* x14 = (const unsigned short*)&xu;
            #pragma unroll
            for (int i = 0; i < 4; i++){
                outf[((size_t)(b*64 + ocb + i))*HW + gy*256 + gx] = bf2f(x14[i]) + acc[m][n][i];
            }
        }
    }
}

// ---------------------------------------------------------------------------
extern "C" void kernel_launch(void* const* d_in, const int* in_sizes, int n_in,
                              void* d_out, int out_size, void* d_ws, size_t ws_size,
                              hipStream_t stream)
{
    const float* x     = (const float*)d_in[0];
    const float* ref   = (const float*)d_in[1];
    const float* ln1w  = (const float*)d_in[2];
    const float* ln1b  = (const float*)d_in[3];
    const float* ln2w  = (const float*)d_in[4];
    const float* ln2b  = (const float*)d_in[5];
    const float* ln3w  = (const float*)d_in[6];
    const float* ln3b  = (const float*)d_in[7];
    const float* wkv   = (const float*)d_in[8];
    const float* wkvdw = (const float*)d_in[9];
    const float* wq    = (const float*)d_in[10];
    const float* wqdw  = (const float*)d_in[11];
    const float* wproj = (const float*)d_in[12];
    const float* temp  = (const float*)d_in[13];
    const float* wadd1 = (const float*)d_in[14];
    const float* wadd2 = (const float*)d_in[15];
    const float* wmul1 = (const float*)d_in[16];
    const float* wfuse = (const float*)d_in[17];
    float* out = (float*)d_out;

    const size_t S = (size_t)4 * 64 * HW;   // 16,777,216 elements per tensor
    float* ws = (float*)d_ws;
    float* b0   = ws;            // kpre -> v ; then z_bf (bf16)
    float* b1   = ws + S;        // vpre ; then y_bf | x1_bf (bf16 halves)
    float* b2   = ws + 2*S;      // qpre -> k ; then t1_bf | t2_bf (bf16 halves)
    float* dots = ws + 3*S;      // 4096
    float* sqq  = dots + 4096;   // 256
    float* sqk  = sqq + 256;     // 256
    float* attn = sqk + 256;     // 4096 (unused, layout stability)
    unsigned short* Wt   = (unsigned short*)(attn + 4096);  // 4*36864 bf16
    unsigned short* Mhi  = Wt + 4*36864;                    // 4*4096 bf16
    unsigned short* Mlo  = Mhi + 4*4096;                    // 4*4096 bf16
    unsigned short* WHhi = Mlo + 4*4096;                    // 12288 bf16
    unsigned short* WHlo = WHhi + 12288;                    // 12288 bf16
    if (ws_size < 3*S*4 + 8704*4 + (4*36864 + 2*4*4096 + 2*12288)*2) return;

    unsigned short* y_bf  = (unsigned short*)b1;
    unsigned short* x1_bf = (unsigned short*)b1 + S;
    unsigned short* t1_bf = (unsigned short*)b2;
    unsigned short* t2_bf = (unsigned short*)b2 + S;
    unsigned short* z_bf  = (unsigned short*)b0;

    // weight prep (independent): 147456 SFM taps + 12288 kv/q hi/lo rows
    k_wprep<<<624, 256, 0, stream>>>(wadd1, wadd2, wmul1, wfuse, wkv, wq,
                                     Wt, WHhi, WHlo);

    // LN1/LN3 + 1x1 convs (MFMA): kpre->b0, vpre->b1, qpre->b2 (block 0 zeroes dots)
    k_ln_1x1_mfma<<<1024, 256, 0, stream>>>(x, ref, ln1w, ln1b, ln3w, ln3b,
                                            WHhi, WHlo, b0, b1, b2, dots);
    // depthwise 3x3: q (b2->out), k (b0->b2), v (b1->b0)
    dim3 gdw(2, 32, 256);
    k_dw3x3<<<gdw, 256, 0, stream>>>(b2, wqdw,         out);
    k_dw3x3<<<gdw, 256, 0, stream>>>(b0, wkvdw,        b2);
    k_dw3x3<<<gdw, 256, 0, stream>>>(b1, wkvdw + 64*9, b0);

    // q.kT dots + sum-sq via MFMA (q in out, k in b2)
    k_qk_mfma<<<1024, 256, 0, stream>>>(out, b2, dots, sqq, sqk);
    // softmax + fold proj into per-batch M = wproj @ blockdiag(A)
    k_softmax_m<<<4, 256, 0, stream>>>(dots, sqq, sqk, temp, wproj, Mhi, Mlo);

    // x1 = x + M.v (MFMA) ; y = LN2(x1) -> bf16 NHWC
    k_attnv_mfma<<<1024, 256, 0, stream>>>(b0, x, Mhi, Mlo, ln2w, ln2b,
                                           x1_bf, y_bf);

    // SFM: 3 fused MFMA conv kernels. Wt taps: [0]=wadd1 [1]=wadd2 [2]=wmul1 [3]=wfuse
    dim3 gc(2, 128, 4);
    k_conv_dual<<<gc, 256, 0, stream>>>(y_bf, Wt + 0*36864, Wt + 2*36864,
                                        t1_bf, t2_bf);                 // t1, t2
    k_conv_zfuse<<<gc, 256, 0, stream>>>(t1_bf, t2_bf, Wt + 1*36864,
                                         Wt + 2*36864, y_bf, z_bf);    // z
    k_conv_final<<<gc, 256, 0, stream>>>(z_bf, Wt + 3*36864, x1_bf, out); // out
}

// Round 9
// 680.456 us; speedup vs baseline: 1.1774x; 1.1774x over previous
//
#include <hip/hip_runtime.h>
#include <math.h>

#define HW 65536
#define NPOS 262144   // B*HW

typedef __attribute__((ext_vector_type(8))) short short8;
typedef __attribute__((ext_vector_type(4))) float float4v;

__device__ __forceinline__ float gelu_exact(float v){
    return 0.5f * v * (1.0f + erff(v * 0.70710678118654752f));
}
__device__ __forceinline__ float sigmoid_(float v){
    return 1.0f / (1.0f + __expf(-v));
}
__device__ __forceinline__ unsigned short f2bf(float f){
    unsigned u = __builtin_bit_cast(unsigned, f);
    unsigned r = (u + 0x7fffu + ((u >> 16) & 1u)) >> 16;
    return (unsigned short)r;
}
__device__ __forceinline__ float bf2f(unsigned short h){
    unsigned u = ((unsigned)h) << 16;
    return __builtin_bit_cast(float, u);
}

// ---------------------------------------------------------------------------
// K0: weight prep.
//  gid < 147456: 4 SFM 3x3 weights [oc][ic][9] fp32 -> [w][tap][oc][ic] bf16
//  gid >= 147456: wkv/wq 1x1 weights fp32 -> hi/lo bf16 [192 rows][64 ic]
// ---------------------------------------------------------------------------
__global__ __launch_bounds__(256) void k_wprep(
    const float* __restrict__ w0, const float* __restrict__ w1,
    const float* __restrict__ w2, const float* __restrict__ w3,
    const float* __restrict__ wkv, const float* __restrict__ wq,
    unsigned short* __restrict__ dst,
    unsigned short* __restrict__ whi, unsigned short* __restrict__ wlo)
{
    int gid = blockIdx.x * 256 + threadIdx.x;
    if (gid < 147456){
        int w = gid / 36864;
        int rem = gid - w * 36864;
        int t = rem >> 12;            // tap
        int oi = rem & 4095;
        int oc = oi >> 6, ic = oi & 63;
        const float* src = (w == 0) ? w0 : (w == 1) ? w1 : (w == 2) ? w2 : w3;
        dst[gid] = f2bf(src[oc*576 + ic*9 + t]);
    } else {
        int e = gid - 147456;         // < 12288
        int row = e >> 6;
        float f = (row < 128) ? wkv[e] : wq[e - 8192];
        unsigned short h = f2bf(f);
        whi[e] = h;
        wlo[e] = f2bf(f - bf2f(h));
    }
}

// ---------------------------------------------------------------------------
// K1: LN1(ref) -> 1x1 w_kv (k_pre,v_pre) ; LN3(x) -> 1x1 w_q (q_pre)
// MFMA version, hi/lo bf16 split for fp32-class precision. W fragments
// direct from global (loaded once per phase, amortized over n-loop --
// NOT per-tap; see R8 post-mortem); LDS = X buffers only -> 2 blocks/CU.
// ---------------------------------------------------------------------------
__global__ __launch_bounds__(256, 2) void k_ln_1x1_mfma(
    const float* __restrict__ x, const float* __restrict__ ref,
    const float* __restrict__ ln1w, const float* __restrict__ ln1b,
    const float* __restrict__ ln3w, const float* __restrict__ ln3b,
    const unsigned short* __restrict__ whi, const unsigned short* __restrict__ wlo,
    float* __restrict__ kpre, float* __restrict__ vpre, float* __restrict__ qpre,
    float* __restrict__ zbuf)
{
    __shared__ unsigned short Xhi[256*72];   // 36864 B
    __shared__ unsigned short Xlo[256*72];   // 36864 B
    __shared__ float s_ln[4][64];            // ln1w, ln1b, ln3w, ln3b

    int t = threadIdx.x;
    int b = blockIdx.x >> 8;                 // 4 batches x 256 tiles
    int pos0 = (blockIdx.x & 255) << 8;

    if (blockIdx.x == 0){
        for (int j = t; j < 4608; j += 256) zbuf[j] = 0.f;
    }
    if (t < 64){
        s_ln[0][t] = ln1w[t]; s_ln[1][t] = ln1b[t];
        s_ln[2][t] = ln3w[t]; s_ln[3][t] = ln3b[t];
    }

    int pos = pos0 + t;
    const size_t base = (size_t)b * 64 * HW + pos;
    int wave = t >> 6, lane = t & 63;
    int q = lane >> 4, l = lane & 15;
    int pb = wave * 64;

    // ---- P1: LN1(ref) -> Xhi/Xlo ----
    {
        float v[64];
        float s = 0.f, ss = 0.f;
        #pragma unroll
        for (int c = 0; c < 64; c++){ float r = ref[base + (size_t)c*HW]; v[c] = r; s += r; ss += r*r; }
        float mu  = s * (1.0f/64.0f);
        float var = ss * (1.0f/64.0f) - mu*mu;
        float inv = rsqrtf(var + 1e-5f);
        __syncthreads();   // s_ln visible
        #pragma unroll
        for (int c0 = 0; c0 < 64; c0 += 8){
            unsigned short h8[8], l8[8];
            #pragma unroll
            for (int i = 0; i < 8; i++){
                float f = (v[c0+i]-mu)*inv*s_ln[0][c0+i] + s_ln[1][c0+i];
                unsigned short h = f2bf(f);
                h8[i] = h; l8[i] = f2bf(f - bf2f(h));
            }
            *(short8*)(&Xhi[t*72 + c0]) = *(short8*)h8;
            *(short8*)(&Xlo[t*72 + c0]) = *(short8*)l8;
        }
    }
    __syncthreads();

    // ---- P2: kv GEMM: 128 oc x 64 px per wave ----
    {
        float4v acc[8][4];
        #pragma unroll
        for (int m = 0; m < 8; m++)
            #pragma unroll
            for (int n = 0; n < 4; n++) acc[m][n] = (float4v){0.f,0.f,0.f,0.f};
        #pragma unroll
        for (int c = 0; c < 2; c++){
            short8 ah[8], al[8];
            #pragma unroll
            for (int m = 0; m < 8; m++){
                ah[m] = *(const short8*)(whi + (m*16 + l)*64 + c*32 + q*8);
                al[m] = *(const short8*)(wlo + (m*16 + l)*64 + c*32 + q*8);
            }
            #pragma unroll
            for (int n = 0; n < 4; n++){
                short8 bh = *(const short8*)(&Xhi[(pb + n*16 + l)*72 + c*32 + q*8]);
                short8 bl = *(const short8*)(&Xlo[(pb + n*16 + l)*72 + c*32 + q*8]);
                #pragma unroll
                for (int m = 0; m < 8; m++){
                    acc[m][n] = __builtin_amdgcn_mfma_f32_16x16x32_bf16(ah[m], bh, acc[m][n], 0, 0, 0);
                    acc[m][n] = __builtin_amdgcn_mfma_f32_16x16x32_bf16(ah[m], bl, acc[m][n], 0, 0, 0);
                    acc[m][n] = __builtin_amdgcn_mfma_f32_16x16x32_bf16(al[m], bh, acc[m][n], 0, 0, 0);
                }
            }
        }
        #pragma unroll
        for (int m = 0; m < 8; m++){
            #pragma unroll
            for (int n = 0; n < 4; n++){
                int px = pos0 + pb + n*16 + l;
                #pragma unroll
                for (int i = 0; i < 4; i++){
                    int oc = m*16 + q*4 + i;
                    float val = acc[m][n][i];
                    if (m < 4) kpre[(size_t)(b*64 + oc)*HW + px] = val;
                    else       vpre[(size_t)(b*64 + (oc-64))*HW + px] = val;
                }
            }
        }
    }
    __syncthreads();

    // ---- P3: LN3(x) -> Xhi/Xlo ----
    {
        float v[64];
        float s = 0.f, ss = 0.f;
        #pragma unroll
        for (int c = 0; c < 64; c++){ float r = x[base + (size_t)c*HW]; v[c] = r; s += r; ss += r*r; }
        float mu  = s * (1.0f/64.0f);
        float var = ss * (1.0f/64.0f) - mu*mu;
        float inv = rsqrtf(var + 1e-5f);
        #pragma unroll
        for (int c0 = 0; c0 < 64; c0 += 8){
            unsigned short h8[8], l8[8];
            #pragma unroll
            for (int i = 0; i < 8; i++){
                float f = (v[c0+i]-mu)*inv*s_ln[2][c0+i] + s_ln[3][c0+i];
                unsigned short h = f2bf(f);
                h8[i] = h; l8[i] = f2bf(f - bf2f(h));
            }
            *(short8*)(&Xhi[t*72 + c0]) = *(short8*)h8;
            *(short8*)(&Xlo[t*72 + c0]) = *(short8*)l8;
        }
    }
    __syncthreads();

    // ---- P4: q GEMM: 64 oc x 64 px per wave (weight rows 128..191) ----
    {
        float4v acc[4][4];
        #pragma unroll
        for (int m = 0; m < 4; m++)
            #pragma unroll
            for (int n = 0; n < 4; n++) acc[m][n] = (float4v){0.f,0.f,0.f,0.f};
        #pragma unroll
        for (int c = 0; c < 2; c++){
            short8 ah[4], al[4];
            #pragma unroll
            for (int m = 0; m < 4; m++){
                ah[m] = *(const short8*)(whi + (128 + m*16 + l)*64 + c*32 + q*8);
                al[m] = *(const short8*)(wlo + (128 + m*16 + l)*64 + c*32 + q*8);
            }
            #pragma unroll
            for (int n = 0; n < 4; n++){
                short8 bh = *(const short8*)(&Xhi[(pb + n*16 + l)*72 + c*32 + q*8]);
                short8 bl = *(const short8*)(&Xlo[(pb + n*16 + l)*72 + c*32 + q*8]);
                #pragma unroll
                for (int m = 0; m < 4; m++){
                    acc[m][n] = __builtin_amdgcn_mfma_f32_16x16x32_bf16(ah[m], bh, acc[m][n], 0, 0, 0);
                    acc[m][n] = __builtin_amdgcn_mfma_f32_16x16x32_bf16(ah[m], bl, acc[m][n], 0, 0, 0);
                    acc[m][n] = __builtin_amdgcn_mfma_f32_16x16x32_bf16(al[m], bh, acc[m][n], 0, 0, 0);
                }
            }
        }
        #pragma unroll
        for (int m = 0; m < 4; m++){
            #pragma unroll
            for (int n = 0; n < 4; n++){
                int px = pos0 + pb + n*16 + l;
                #pragma unroll
                for (int i = 0; i < 4; i++){
                    int oc = m*16 + q*4 + i;
                    qpre[(size_t)(b*64 + oc)*HW + px] = acc[m][n][i];
                }
            }
        }
    }
}

// ---------------------------------------------------------------------------
// K2: depthwise 3x3, pad 1 (fp32 NCHW). Vectorized: 128-px tiles, each
// thread computes 4 px with float4 store.
// ---------------------------------------------------------------------------
__global__ __launch_bounds__(256) void k_dw3x3(
    const float* __restrict__ in, const float* __restrict__ w9,
    float* __restrict__ out)
{
    __shared__ float s_in[10*132];
    int t  = threadIdx.x;
    int b  = blockIdx.z >> 6, ch = blockIdx.z & 63;
    int x0 = blockIdx.x * 128, y0 = blockIdx.y * 8;
    const float* src = in + (size_t)(b*64+ch)*HW;
    for (int j = t; j < 1300; j += 256){
        int r = j / 130, cc = j - r*130;
        int gy = y0 - 1 + r, gx = x0 - 1 + cc;
        float val = 0.f;
        if (gy >= 0 && gy < 256 && gx >= 0 && gx < 256) val = src[gy*256 + gx];
        s_in[r*132 + cc] = val;
    }
    float w[9];
    #pragma unroll
    for (int k = 0; k < 9; k++) w[k] = w9[ch*9 + k];
    __syncthreads();
    int ty = t >> 5, tx4 = (t & 31) << 2;
    float o[4] = {0.f, 0.f, 0.f, 0.f};
    #pragma unroll
    for (int ky = 0; ky < 3; ky++){
        float f[6];
        #pragma unroll
        for (int i = 0; i < 6; i++) f[i] = s_in[(ty+ky)*132 + tx4 + i];
        #pragma unroll
        for (int px = 0; px < 4; px++){
            o[px] += w[ky*3+0] * f[px];
            o[px] += w[ky*3+1] * f[px+1];
            o[px] += w[ky*3+2] * f[px+2];
        }
    }
    *(float4v*)(&out[(size_t)(b*64+ch)*HW + (y0+ty)*256 + x0 + tx4]) = *(float4v*)o;
}

// ---------------------------------------------------------------------------
// K3: q.kT dots via MFMA (hi/lo bf16 3-term) + fused per-channel sum-sq.
// No LDS; frags straight from global. (R7 verified.)
// ---------------------------------------------------------------------------
__global__ __launch_bounds__(256) void k_qk_mfma(
    const float* __restrict__ q, const float* __restrict__ k,
    float* __restrict__ dots, float* __restrict__ sqq, float* __restrict__ sqk)
{
    int t = threadIdx.x;
    int b = blockIdx.x >> 8;
    int p0 = (blockIdx.x & 255) * 256;
    int wave = t >> 6, lane = t & 63;
    int h = wave;
    int row = lane & 15, kg = lane >> 4;

    const float* qrow = q + (size_t)(b*64 + h*16 + row)*HW;
    const float* krow = k + (size_t)(b*64 + h*16 + row)*HW;

    float4v acc = (float4v){0.f, 0.f, 0.f, 0.f};
    float sq = 0.f, sk = 0.f;

    for (int step = 0; step < 8; step++){
        int p = p0 + step*32 + kg*8;
        float qa[8], ka[8];
        #pragma unroll
        for (int j = 0; j < 8; j++){ qa[j] = qrow[p+j]; ka[j] = krow[p+j]; }
        unsigned short qh8[8], ql8[8], kh8[8], kl8[8];
        #pragma unroll
        for (int j = 0; j < 8; j++){
            sq += qa[j]*qa[j];
            sk += ka[j]*ka[j];
            unsigned short hh = f2bf(qa[j]);
            qh8[j] = hh; ql8[j] = f2bf(qa[j] - bf2f(hh));
            hh = f2bf(ka[j]);
            kh8[j] = hh; kl8[j] = f2bf(ka[j] - bf2f(hh));
        }
        short8 ah = *(short8*)qh8, al = *(short8*)ql8;
        short8 bh = *(short8*)kh8, bl = *(short8*)kl8;
        acc = __builtin_amdgcn_mfma_f32_16x16x32_bf16(ah, bh, acc, 0, 0, 0);
        acc = __builtin_amdgcn_mfma_f32_16x16x32_bf16(ah, bl, acc, 0, 0, 0);
        acc = __builtin_amdgcn_mfma_f32_16x16x32_bf16(al, bh, acc, 0, 0, 0);
    }

    // sum-sq reduce across kg groups (lanes row, row+16, row+32, row+48)
    sq += __shfl_xor(sq, 16); sq += __shfl_xor(sq, 32);
    sk += __shfl_xor(sk, 16); sk += __shfl_xor(sk, 32);
    if (lane < 16){
        atomicAdd(&sqq[b*64 + h*16 + row], sq);
        atomicAdd(&sqk[b*64 + h*16 + row], sk);
    }
    // C layout: cq = kg*4 + i, cd = row
    int dbase = ((b*4 + h)*16 + kg*4)*16 + row;
    atomicAdd(&dots[dbase + 0*16], acc[0]);
    atomicAdd(&dots[dbase + 1*16], acc[1]);
    atomicAdd(&dots[dbase + 2*16], acc[2]);
    atomicAdd(&dots[dbase + 3*16], acc[3]);
}

// ---------------------------------------------------------------------------
// K4: normalize + temperature + softmax over d, then fold the projection:
// M_b = Wproj @ blockdiag(A_b)  ->  x1 = x + M_b . v  (single GEMM later).
// ---------------------------------------------------------------------------
__global__ __launch_bounds__(256) void k_softmax_m(
    const float* __restrict__ dots, const float* __restrict__ sqq,
    const float* __restrict__ sqk, const float* __restrict__ temp,
    const float* __restrict__ wproj,
    unsigned short* __restrict__ Mhi, unsigned short* __restrict__ Mlo)
{
    __shared__ float s_wp[4096];
    __shared__ float s_at[1024];
    int t = threadIdx.x;
    int b = blockIdx.x;

    for (int j = t; j < 4096; j += 256) s_wp[j] = wproj[j];

    if (t < 64){
        int h = t >> 4, cq = t & 15;
        float nq = fmaxf(sqrtf(sqq[b*64 + h*16 + cq]), 1e-12f);
        float tp = temp[h];
        float l[16];
        float m = -1e30f;
        #pragma unroll
        for (int d = 0; d < 16; d++){
            float nk = fmaxf(sqrtf(sqk[b*64 + h*16 + d]), 1e-12f);
            float v = dots[((b*4+h)*16 + cq)*16 + d] / (nq*nk) * tp;
            l[d] = v; m = fmaxf(m, v);
        }
        float s = 0.f;
        #pragma unroll
        for (int d = 0; d < 16; d++){ l[d] = __expf(l[d]-m); s += l[d]; }
        float invs = 1.0f / s;
        #pragma unroll
        for (int d = 0; d < 16; d++) s_at[(h*16 + cq)*16 + d] = l[d]*invs;
    }
    __syncthreads();

    // M: 4096 entries, 16 each
    for (int e = t; e < 4096; e += 256){
        int c = e >> 6, kk = e & 63;
        int h = kk >> 4, d = kk & 15;
        float a = 0.f;
        #pragma unroll
        for (int r = 0; r < 16; r++)
            a += s_wp[c*64 + h*16 + r] * s_at[(h*16 + r)*16 + d];
        unsigned short hh = f2bf(a);
        Mhi[b*4096 + e] = hh;
        Mlo[b*4096 + e] = f2bf(a - bf2f(hh));
    }
}

// ---------------------------------------------------------------------------
// K5: x1 = x + M_b.v  (MFMA, hi/lo bf16 3-term) ; y = LN2(x1).
// Emit x1 and y as bf16 NHWC [b][y][x][c] for the MFMA SFM convs.
// ---------------------------------------------------------------------------
__global__ __launch_bounds__(256, 2) void k_attnv_mfma(
    const float* __restrict__ v, const float* __restrict__ x,
    const unsigned short* __restrict__ Mhi_g, const unsigned short* __restrict__ Mlo_g,
    const float* __restrict__ ln2w, const float* __restrict__ ln2b,
    unsigned short* __restrict__ x1_bf, unsigned short* __restrict__ y_bf)
{
    __shared__ unsigned short Mhi[64*72];    // 9216 B
    __shared__ unsigned short Mlo[64*72];    // 9216 B
    __shared__ float s_lw[64], s_lb[64];
    int t = threadIdx.x;
    int b = blockIdx.x >> 8;
    int pos0 = (blockIdx.x & 255) << 8;

    for (int e = t; e < 4096; e += 256){
        int row = e >> 6, ic = e & 63;
        Mhi[row*72 + ic] = Mhi_g[b*4096 + e];
        Mlo[row*72 + ic] = Mlo_g[b*4096 + e];
    }
    if (t < 64){ s_lw[t] = ln2w[t]; s_lb[t] = ln2b[t]; }
    __syncthreads();

    int wave = t >> 6, lane = t & 63;
    int q = lane >> 4, l = lane & 15;
    int px0 = pos0 + wave*64;                // wave's 64-px slab

    float4v acc[4][4];
    #pragma unroll
    for (int m = 0; m < 4; m++)
        #pragma unroll
        for (int n = 0; n < 4; n++) acc[m][n] = (float4v){0.f,0.f,0.f,0.f};

    #pragma unroll
    for (int c = 0; c < 2; c++){
        short8 ah[4], al[4];
        #pragma unroll
        for (int m = 0; m < 4; m++){
            ah[m] = *(const short8*)(&Mhi[(m*16 + l)*72 + c*32 + q*8]);
            al[m] = *(const short8*)(&Mlo[(m*16 + l)*72 + c*32 + q*8]);
        }
        #pragma unroll
        for (int n = 0; n < 4; n++){
            float vv[8];
            #pragma unroll
            for (int j = 0; j < 8; j++)
                vv[j] = v[(size_t)(b*64 + c*32 + q*8 + j)*HW + px0 + n*16 + l];
            unsigned short bh8[8], bl8[8];
            #pragma unroll
            for (int j = 0; j < 8; j++){
                unsigned short h = f2bf(vv[j]);
                bh8[j] = h; bl8[j] = f2bf(vv[j] - bf2f(h));
            }
            short8 bh = *(short8*)bh8, bl = *(short8*)bl8;
            #pragma unroll
            for (int m = 0; m < 4; m++){
                acc[m][n] = __builtin_amdgcn_mfma_f32_16x16x32_bf16(ah[m], bh, acc[m][n], 0, 0, 0);
                acc[m][n] = __builtin_amdgcn_mfma_f32_16x16x32_bf16(ah[m], bl, acc[m][n], 0, 0, 0);
                acc[m][n] = __builtin_amdgcn_mfma_f32_16x16x32_bf16(al[m], bh, acc[m][n], 0, 0, 0);
            }
        }
    }

    // epilogue: per n-tile -> x-add, LN2 stats via shfl over q, pack bf16
    #pragma unroll
    for (int n = 0; n < 4; n++){
        int px = px0 + n*16 + l;
        float val[4][4];
        float sn = 0.f, ssn = 0.f;
        #pragma unroll
        for (int m = 0; m < 4; m++){
            #pragma unroll
            for (int i = 0; i < 4; i++){
                float f = acc[m][n][i] + x[(size_t)(b*64 + m*16 + q*4 + i)*HW + px];
                val[m][i] = f; sn += f; ssn += f*f;
            }
        }
        sn  += __shfl_xor(sn, 16);  sn  += __shfl_xor(sn, 32);
        ssn += __shfl_xor(ssn, 16); ssn += __shfl_xor(ssn, 32);
        float mu  = sn * (1.0f/64.0f);
        float var = ssn * (1.0f/64.0f) - mu*mu;
        float inv = rsqrtf(var + 1e-5f);
        size_t nb = ((size_t)b*HW + px) * 64;
        #pragma unroll
        for (int m = 0; m < 4; m++){
            int ocb = m*16 + q*4;
            unsigned short xv[4], yv[4];
            #pragma unroll
            for (int i = 0; i < 4; i++){
                float f = val[m][i];
                xv[i] = f2bf(f);
                yv[i] = f2bf((f - mu) * inv * s_lw[ocb+i] + s_lb[ocb+i]);
            }
            *(unsigned long long*)(x1_bf + nb + ocb) = *(unsigned long long*)xv;
            *(unsigned long long*)(y_bf  + nb + ocb) = *(unsigned long long*)yv;
        }
    }
}

// ---------------------------------------------------------------------------
// K6a: fused dual 3x3 conv over y: t1 = gelu(conv(y,wA)), t2 = gelu(conv(y,wB)).
// One X staging feeds both weight sets. Weights via double-buffered LDS
// (per-tap global loads regressed -- R8 post-mortem). 62KB LDS -> 2 blk/CU.
// ---------------------------------------------------------------------------
__global__ __launch_bounds__(256, 2) void k_conv_dual(
    const unsigned short* __restrict__ in,
    const unsigned short* __restrict__ wtA,
    const unsigned short* __restrict__ wtB,
    unsigned short* __restrict__ o1,
    unsigned short* __restrict__ o2)
{
    __shared__ unsigned short Xs[4*130*40];   // 41600 B
    __shared__ unsigned short WsA[2][64*40];  // 10240 B
    __shared__ unsigned short WsB[2][64*40];  // 10240 B
    int tid  = threadIdx.x;
    int b    = blockIdx.z;
    int y0   = blockIdx.y * 2;
    int x0   = blockIdx.x * 128;
    int wave = tid >> 6, lane = tid & 63;
    int q = lane >> 4, l = lane & 15;
    int r = wave >> 1;
    int pb = (wave & 1) * 64;

    float4v accA[4][4], accB[4][4];
    #pragma unroll
    for (int m = 0; m < 4; m++)
        #pragma unroll
        for (int n = 0; n < 4; n++){
            accA[m][n] = (float4v){0.f,0.f,0.f,0.f};
            accB[m][n] = (float4v){0.f,0.f,0.f,0.f};
        }

    for (int c = 0; c < 2; ++c){
        __syncthreads();
        for (int j = tid; j < 2080; j += 256){
            int row = j / 520;
            int rem = j - row*520;
            int px  = rem >> 2;
            int part= rem & 3;
            int gy = y0 - 1 + row, gx = x0 - 1 + px;
            short8 v = (short8)0;
            if (gy >= 0 && gy < 256 && gx >= 0 && gx < 256){
                v = *(const short8*)(in + (((size_t)b*HW + gy*256 + gx) * 64) + c*32 + part*8);
            }
            *(short8*)(&Xs[(row*130 + px)*40 + part*8]) = v;
        }
        {
            int oc = tid >> 2, part = tid & 3;
            *(short8*)(&WsA[0][oc*40 + part*8]) =
                *(const short8*)(wtA + ((size_t)(0*64 + oc))*64 + c*32 + part*8);
            *(short8*)(&WsB[0][oc*40 + part*8]) =
                *(const short8*)(wtB + ((size_t)(0*64 + oc))*64 + c*32 + part*8);
        }
        for (int t = 0; t < 9; ++t){
            __syncthreads();
            if (t < 8){
                int oc = tid >> 2, part = tid & 3;
                *(short8*)(&WsA[(t+1)&1][oc*40 + part*8]) =
                    *(const short8*)(wtA + ((size_t)((t+1)*64 + oc))*64 + c*32 + part*8);
                *(short8*)(&WsB[(t+1)&1][oc*40 + part*8]) =
                    *(const short8*)(wtB + ((size_t)((t+1)*64 + oc))*64 + c*32 + part*8);
            }
            int ky = t / 3, kx = t - ky*3;
            const unsigned short* wa = &WsA[t & 1][0];
            const unsigned short* wb = &WsB[t & 1][0];
            short8 afrA[4], afrB[4];
            #pragma unroll
            for (int m = 0; m < 4; m++){
                afrA[m] = *(const short8*)(wa + (m*16 + l)*40 + q*8);
                afrB[m] = *(const short8*)(wb + (m*16 + l)*40 + q*8);
            }
            #pragma unroll
            for (int n = 0; n < 4; n++){
                int px = pb + n*16 + l;
                short8 bfr = *(const short8*)(&Xs[((r+ky)*130 + px + kx)*40 + q*8]);
                #pragma unroll
                for (int m = 0; m < 4; m++){
                    accA[m][n] = __builtin_amdgcn_mfma_f32_16x16x32_bf16(afrA[m], bfr, accA[m][n], 0, 0, 0);
                    accB[m][n] = __builtin_amdgcn_mfma_f32_16x16x32_bf16(afrB[m], bfr, accB[m][n], 0, 0, 0);
                }
            }
        }
    }

    int gy = y0 + r;
    #pragma unroll
    for (int n = 0; n < 4; n++){
        int gx = x0 + pb + n*16 + l;
        size_t pixbase = ((size_t)b*HW + gy*256 + gx) * 64;
        #pragma unroll
        for (int m = 0; m < 4; m++){
            int ocb = m*16 + q*4;
            unsigned short p1[4], p2[4];
            #pragma unroll
            for (int i = 0; i < 4; i++){
                p1[i] = f2bf(gelu_exact(accA[m][n][i]));
                p2[i] = f2bf(gelu_exact(accB[m][n][i]));
            }
            *(unsigned long long*)(o1 + pixbase + ocb) = *(unsigned long long*)p1;
            *(unsigned long long*)(o2 + pixbase + ocb) = *(unsigned long long*)p2;
        }
    }
}

// ---------------------------------------------------------------------------
// K6b: fused z kernel: z = y * sigmoid(conv(t2,wB)) + conv(t1,wA).
// Per c-chunk and pass: stage X + double-buffered Ws (R7 weight path).
// xadd intermediate eliminated; add uses fp32 accA directly.
// ---------------------------------------------------------------------------
__global__ __launch_bounds__(256, 3) void k_conv_zfuse(
    const unsigned short* __restrict__ in1,   // t1
    const unsigned short* __restrict__ in2,   // t2
    const unsigned short* __restrict__ wtA,   // wadd2
    const unsigned short* __restrict__ wtB,   // wmul1
    const unsigned short* __restrict__ yb,    // y_bf
    unsigned short* __restrict__ zo)
{
    __shared__ unsigned short Xs[4*130*40];   // 41600 B
    __shared__ unsigned short Ws[2][64*40];   // 10240 B
    int tid  = threadIdx.x;
    int b    = blockIdx.z;
    int y0   = blockIdx.y * 2;
    int x0   = blockIdx.x * 128;
    int wave = tid >> 6, lane = tid & 63;
    int q = lane >> 4, l = lane & 15;
    int r = wave >> 1;
    int pb = (wave & 1) * 64;

    float4v accA[4][4], accB[4][4];
    #pragma unroll
    for (int m = 0; m < 4; m++)
        #pragma unroll
        for (int n = 0; n < 4; n++){
            accA[m][n] = (float4v){0.f,0.f,0.f,0.f};
            accB[m][n] = (float4v){0.f,0.f,0.f,0.f};
        }

    for (int c = 0; c < 2; ++c){
        #pragma unroll
        for (int pass = 0; pass < 2; ++pass){
            const unsigned short* src = (pass == 0) ? in1 : in2;
            const unsigned short* wt  = (pass == 0) ? wtA : wtB;
            __syncthreads();
            for (int j = tid; j < 2080; j += 256){
                int row = j / 520;
                int rem = j - row*520;
                int px  = rem >> 2;
                int part= rem & 3;
                int gy = y0 - 1 + row, gx = x0 - 1 + px;
                short8 v = (short8)0;
                if (gy >= 0 && gy < 256 && gx >= 0 && gx < 256){
                    v = *(const short8*)(src + (((size_t)b*HW + gy*256 + gx) * 64) + c*32 + part*8);
                }
                *(short8*)(&Xs[(row*130 + px)*40 + part*8]) = v;
            }
            {
                int oc = tid >> 2, part = tid & 3;
                *(short8*)(&Ws[0][oc*40 + part*8]) =
                    *(const short8*)(wt + ((size_t)(0*64 + oc))*64 + c*32 + part*8);
            }
            for (int t = 0; t < 9; ++t){
                __syncthreads();
                if (t < 8){
                    int oc = tid >> 2, part = tid & 3;
                    *(short8*)(&Ws[(t+1)&1][oc*40 + part*8]) =
                        *(const short8*)(wt + ((size_t)((t+1)*64 + oc))*64 + c*32 + part*8);
                }
                int ky = t / 3, kx = t - ky*3;
                const unsigned short* wb = &Ws[t & 1][0];
                short8 afr[4];
                #pragma unroll
                for (int m = 0; m < 4; m++)
                    afr[m] = *(const short8*)(wb + (m*16 + l)*40 + q*8);
                #pragma unroll
                for (int n = 0; n < 4; n++){
                    int px = pb + n*16 + l;
                    short8 bfr = *(const short8*)(&Xs[((r+ky)*130 + px + kx)*40 + q*8]);
                    #pragma unroll
                    for (int m = 0; m < 4; m++){
                        if (pass == 0)
                            accA[m][n] = __builtin_amdgcn_mfma_f32_16x16x32_bf16(afr[m], bfr, accA[m][n], 0, 0, 0);
                        else
                            accB[m][n] = __builtin_amdgcn_mfma_f32_16x16x32_bf16(afr[m], bfr, accB[m][n], 0, 0, 0);
                    }
                }
            }
        }
    }

    int gy = y0 + r;
    #pragma unroll
    for (int n = 0; n < 4; n++){
        int gx = x0 + pb + n*16 + l;
        size_t pixbase = ((size_t)b*HW + gy*256 + gx) * 64;
        #pragma unroll
        for (int m = 0; m < 4; m++){
            int ocb = m*16 + q*4;
            unsigned long long yu = *(const unsigned long long*)(yb + pixbase + ocb);
            const unsigned short* y4 = (const unsigned short*)&yu;
            unsigned short pk[4];
            #pragma unroll
            for (int i = 0; i < 4; i++){
                float z = bf2f(y4[i]) * sigmoid_(accB[m][n][i]) + accA[m][n][i];
                pk[i] = f2bf(z);
            }
            *(unsigned long long*)(zo + pixbase + ocb) = *(unsigned long long*)pk;
        }
    }
}

// ---------------------------------------------------------------------------
// K6c: final conv: out = x1 + conv(z, wfuse)  (fp32 NCHW out).
// R7 structure: double-buffered Ws LDS.
// ---------------------------------------------------------------------------
__global__ __launch_bounds__(256, 3) void k_conv_final(
    const unsigned short* __restrict__ in,    // z_bf
    const unsigned short* __restrict__ wt,    // wfuse taps
    const unsigned short* __restrict__ x1,    // x1_bf
    float* __restrict__ outf)
{
    __shared__ unsigned short Xs[4*130*40];   // 41600 B
    __shared__ unsigned short Ws[2][64*40];   // 10240 B
    int tid  = threadIdx.x;
    int b    = blockIdx.z;
    int y0   = blockIdx.y * 2;
    int x0   = blockIdx.x * 128;
    int wave = tid >> 6, lane = tid & 63;
    int q = lane >> 4, l = lane & 15;
    int r = wave >> 1;
    int pb = (wave & 1) * 64;

    float4v acc[4][4];
    #pragma unroll
    for (int m = 0; m < 4; m++)
        #pragma unroll
        for (int n = 0; n < 4; n++) acc[m][n] = (float4v){0.f,0.f,0.f,0.f};

    for (int c = 0; c < 2; ++c){
        __syncthreads();
        for (int j = tid; j < 2080; j += 256){
            int row = j / 520;
            int rem = j - row*520;
            int px  = rem >> 2;
            int part= rem & 3;
            int gy = y0 - 1 + row, gx = x0 - 1 + px;
            short8 v = (short8)0;
            if (gy >= 0 && gy < 256 && gx >= 0 && gx < 256){
                v = *(const short8*)(in + (((size_t)b*HW + gy*256 + gx) * 64) + c*32 + part*8);
            }
            *(short8*)(&Xs[(row*130 + px)*40 + part*8]) = v;
        }
        {
            int oc = tid >> 2, part = tid & 3;
            *(short8*)(&Ws[0][oc*40 + part*8]) =
                *(const short8*)(wt + ((size_t)(0*64 + oc))*64 + c*32 + part*8);
        }
        for (int t = 0; t < 9; ++t){
            __syncthreads();
            if (t < 8){
                int oc = tid >> 2, part = tid & 3;
                *(short8*)(&Ws[(t+1)&1][oc*40 + part*8]) =
                    *(const short8*)(wt + ((size_t)((t+1)*64 + oc))*64 + c*32 + part*8);
            }
            int ky = t / 3, kx = t - ky*3;
            const unsigned short* wb = &Ws[t & 1][0];
            short8 afr[4];
            #pragma unroll
            for (int m = 0; m < 4; m++)
                afr[m] = *(const short8*)(wb + (m*16 + l)*40 + q*8);
            #pragma unroll
            for (int n = 0; n < 4; n++){
                int px = pb + n*16 + l;
                short8 bfr = *(const short8*)(&Xs[((r+ky)*130 + px + kx)*40 + q*8]);
                #pragma unroll
                for (int m = 0; m < 4; m++)
                    acc[m][n] = __builtin_amdgcn_mfma_f32_16x16x32_bf16(afr[m], bfr, acc[m][n], 0, 0, 0);
            }
        }
    }

    int gy = y0 + r;
    #pragma unroll
    for (int n = 0; n < 4; n++){
        int gx = x0 + pb + n*16 + l;
        size_t pixbase = ((size_t)b*HW + gy*256 + gx) * 64;
        #pragma unroll
        for (int m = 0; m < 4; m++){
            int ocb = m*16 + q*4;
            unsigned long long xu = *(const unsigned long long*)(x1 + pixbase + ocb);
            const unsigned short* x14 = (const unsigned short*)&xu;
            #pragma unroll
            for (int i = 0; i < 4; i++){
                outf[((size_t)(b*64 + ocb + i))*HW + gy*256 + gx] = bf2f(x14[i]) + acc[m][n][i];
            }
        }
    }
}

// ---------------------------------------------------------------------------
extern "C" void kernel_launch(void* const* d_in, const int* in_sizes, int n_in,
                              void* d_out, int out_size, void* d_ws, size_t ws_size,
                              hipStream_t stream)
{
    const float* x     = (const float*)d_in[0];
    const float* ref   = (const float*)d_in[1];
    const float* ln1w  = (const float*)d_in[2];
    const float* ln1b  = (const float*)d_in[3];
    const float* ln2w  = (const float*)d_in[4];
    const float* ln2b  = (const float*)d_in[5];
    const float* ln3w  = (const float*)d_in[6];
    const float* ln3b  = (const float*)d_in[7];
    const float* wkv   = (const float*)d_in[8];
    const float* wkvdw = (const float*)d_in[9];
    const float* wq    = (const float*)d_in[10];
    const float* wqdw  = (const float*)d_in[11];
    const float* wproj = (const float*)d_in[12];
    const float* temp  = (const float*)d_in[13];
    const float* wadd1 = (const float*)d_in[14];
    const float* wadd2 = (const float*)d_in[15];
    const float* wmul1 = (const float*)d_in[16];
    const float* wfuse = (const float*)d_in[17];
    float* out = (float*)d_out;

    const size_t S = (size_t)4 * 64 * HW;   // 16,777,216 elements per tensor
    float* ws = (float*)d_ws;
    float* b0   = ws;            // kpre -> v ; then z_bf (bf16)
    float* b1   = ws + S;        // vpre ; then y_bf | x1_bf (bf16 halves)
    float* b2   = ws + 2*S;      // qpre -> k ; then t1_bf | t2_bf (bf16 halves)
    float* dots = ws + 3*S;      // 4096
    float* sqq  = dots + 4096;   // 256
    float* sqk  = sqq + 256;     // 256
    float* attn = sqk + 256;     // 4096 (unused, layout stability)
    unsigned short* Wt   = (unsigned short*)(attn + 4096);  // 4*36864 bf16
    unsigned short* Mhi  = Wt + 4*36864;                    // 4*4096 bf16
    unsigned short* Mlo  = Mhi + 4*4096;                    // 4*4096 bf16
    unsigned short* WHhi = Mlo + 4*4096;                    // 12288 bf16
    unsigned short* WHlo = WHhi + 12288;                    // 12288 bf16
    if (ws_size < 3*S*4 + 8704*4 + (4*36864 + 2*4*4096 + 2*12288)*2) return;

    unsigned short* y_bf  = (unsigned short*)b1;
    unsigned short* x1_bf = (unsigned short*)b1 + S;
    unsigned short* t1_bf = (unsigned short*)b2;
    unsigned short* t2_bf = (unsigned short*)b2 + S;
    unsigned short* z_bf  = (unsigned short*)b0;

    // weight prep (independent): 147456 SFM taps + 12288 kv/q hi/lo rows
    k_wprep<<<624, 256, 0, stream>>>(wadd1, wadd2, wmul1, wfuse, wkv, wq,
                                     Wt, WHhi, WHlo);

    // LN1/LN3 + 1x1 convs (MFMA): kpre->b0, vpre->b1, qpre->b2 (block 0 zeroes dots)
    k_ln_1x1_mfma<<<1024, 256, 0, stream>>>(x, ref, ln1w, ln1b, ln3w, ln3b,
                                            WHhi, WHlo, b0, b1, b2, dots);
    // depthwise 3x3: q (b2->out), k (b0->b2), v (b1->b0)
    dim3 gdw(2, 32, 256);
    k_dw3x3<<<gdw, 256, 0, stream>>>(b2, wqdw,         out);
    k_dw3x3<<<gdw, 256, 0, stream>>>(b0, wkvdw,        b2);
    k_dw3x3<<<gdw, 256, 0, stream>>>(b1, wkvdw + 64*9, b0);

    // q.kT dots + sum-sq via MFMA (q in out, k in b2)
    k_qk_mfma<<<1024, 256, 0, stream>>>(out, b2, dots, sqq, sqk);
    // softmax + fold proj into per-batch M = wproj @ blockdiag(A)
    k_softmax_m<<<4, 256, 0, stream>>>(dots, sqq, sqk, temp, wproj, Mhi, Mlo);

    // x1 = x + M.v (MFMA) ; y = LN2(x1) -> bf16 NHWC
    k_attnv_mfma<<<1024, 256, 0, stream>>>(b0, x, Mhi, Mlo, ln2w, ln2b,
                                           x1_bf, y_bf);

    // SFM: 3 fused MFMA conv kernels. Wt taps: [0]=wadd1 [1]=wadd2 [2]=wmul1 [3]=wfuse
    dim3 gc(2, 128, 4);
    k_conv_dual<<<gc, 256, 0, stream>>>(y_bf, Wt + 0*36864, Wt + 2*36864,
                                        t1_bf, t2_bf);                 // t1, t2
    k_conv_zfuse<<<gc, 256, 0, stream>>>(t1_bf, t2_bf, Wt + 1*36864,
                                         Wt + 2*36864, y_bf, z_bf);    // z
    k_conv_final<<<gc, 256, 0, stream>>>(z_bf, Wt + 3*36864, x1_bf, out); // out
}

// Round 10
// 668.888 us; speedup vs baseline: 1.1977x; 1.0173x over previous
//
#include <hip/hip_runtime.h>
#include <math.h>

#define HW 65536
#define NPOS 262144   // B*HW

typedef __attribute__((ext_vector_type(8))) short short8;
typedef __attribute__((ext_vector_type(4))) float float4v;

__device__ __forceinline__ float gelu_exact(float v){
    return 0.5f * v * (1.0f + erff(v * 0.70710678118654752f));
}
__device__ __forceinline__ float sigmoid_(float v){
    return 1.0f / (1.0f + __expf(-v));
}
__device__ __forceinline__ unsigned short f2bf(float f){
    unsigned u = __builtin_bit_cast(unsigned, f);
    unsigned r = (u + 0x7fffu + ((u >> 16) & 1u)) >> 16;
    return (unsigned short)r;
}
__device__ __forceinline__ float bf2f(unsigned short h){
    unsigned u = ((unsigned)h) << 16;
    return __builtin_bit_cast(float, u);
}

// LDS-only barrier: __syncthreads drains vmcnt(0) (all global loads/stores),
// which stalls on in-flight prefetches and store retirement. For reg-staged
// LDS producer/consumer phases only lgkmcnt matters cross-wave.
__device__ __forceinline__ void barrier_lds(){
    asm volatile("s_waitcnt lgkmcnt(0)" ::: "memory");
    __builtin_amdgcn_s_barrier();
}

// ---------------------------------------------------------------------------
// K0: weight prep.
//  gid < 147456: 4 SFM 3x3 weights [oc][ic][9] fp32 -> [w][tap][oc][ic] bf16
//  gid >= 147456: wkv/wq 1x1 weights fp32 -> hi/lo bf16 [192 rows][64 ic]
// ---------------------------------------------------------------------------
__global__ __launch_bounds__(256) void k_wprep(
    const float* __restrict__ w0, const float* __restrict__ w1,
    const float* __restrict__ w2, const float* __restrict__ w3,
    const float* __restrict__ wkv, const float* __restrict__ wq,
    unsigned short* __restrict__ dst,
    unsigned short* __restrict__ whi, unsigned short* __restrict__ wlo)
{
    int gid = blockIdx.x * 256 + threadIdx.x;
    if (gid < 147456){
        int w = gid / 36864;
        int rem = gid - w * 36864;
        int t = rem >> 12;            // tap
        int oi = rem & 4095;
        int oc = oi >> 6, ic = oi & 63;
        const float* src = (w == 0) ? w0 : (w == 1) ? w1 : (w == 2) ? w2 : w3;
        dst[gid] = f2bf(src[oc*576 + ic*9 + t]);
    } else {
        int e = gid - 147456;         // < 12288
        int row = e >> 6;
        float f = (row < 128) ? wkv[e] : wq[e - 8192];
        unsigned short h = f2bf(f);
        whi[e] = h;
        wlo[e] = f2bf(f - bf2f(h));
    }
}

// ---------------------------------------------------------------------------
// K1: LN1(ref) -> 1x1 w_kv (k_pre,v_pre) ; LN3(x) -> 1x1 w_q (q_pre)
// MFMA version, hi/lo bf16 split for fp32-class precision. W fragments
// direct from global (once per phase, amortized); LDS = X buffers only.
// barrier_lds: the P2->P3 barrier no longer waits kpre/vpre store retirement.
// ---------------------------------------------------------------------------
__global__ __launch_bounds__(256, 2) void k_ln_1x1_mfma(
    const float* __restrict__ x, const float* __restrict__ ref,
    const float* __restrict__ ln1w, const float* __restrict__ ln1b,
    const float* __restrict__ ln3w, const float* __restrict__ ln3b,
    const unsigned short* __restrict__ whi, const unsigned short* __restrict__ wlo,
    float* __restrict__ kpre, float* __restrict__ vpre, float* __restrict__ qpre,
    float* __restrict__ zbuf)
{
    __shared__ unsigned short Xhi[256*72];   // 36864 B
    __shared__ unsigned short Xlo[256*72];   // 36864 B
    __shared__ float s_ln[4][64];            // ln1w, ln1b, ln3w, ln3b

    int t = threadIdx.x;
    int b = blockIdx.x >> 8;                 // 4 batches x 256 tiles
    int pos0 = (blockIdx.x & 255) << 8;

    if (blockIdx.x == 0){
        for (int j = t; j < 4608; j += 256) zbuf[j] = 0.f;
    }
    if (t < 64){
        s_ln[0][t] = ln1w[t]; s_ln[1][t] = ln1b[t];
        s_ln[2][t] = ln3w[t]; s_ln[3][t] = ln3b[t];
    }

    int pos = pos0 + t;
    const size_t base = (size_t)b * 64 * HW + pos;
    int wave = t >> 6, lane = t & 63;
    int q = lane >> 4, l = lane & 15;
    int pb = wave * 64;

    // ---- P1: LN1(ref) -> Xhi/Xlo ----
    {
        float v[64];
        float s = 0.f, ss = 0.f;
        #pragma unroll
        for (int c = 0; c < 64; c++){ float r = ref[base + (size_t)c*HW]; v[c] = r; s += r; ss += r*r; }
        float mu  = s * (1.0f/64.0f);
        float var = ss * (1.0f/64.0f) - mu*mu;
        float inv = rsqrtf(var + 1e-5f);
        barrier_lds();   // s_ln visible
        #pragma unroll
        for (int c0 = 0; c0 < 64; c0 += 8){
            unsigned short h8[8], l8[8];
            #pragma unroll
            for (int i = 0; i < 8; i++){
                float f = (v[c0+i]-mu)*inv*s_ln[0][c0+i] + s_ln[1][c0+i];
                unsigned short h = f2bf(f);
                h8[i] = h; l8[i] = f2bf(f - bf2f(h));
            }
            *(short8*)(&Xhi[t*72 + c0]) = *(short8*)h8;
            *(short8*)(&Xlo[t*72 + c0]) = *(short8*)l8;
        }
    }
    barrier_lds();

    // ---- P2: kv GEMM: 128 oc x 64 px per wave ----
    {
        float4v acc[8][4];
        #pragma unroll
        for (int m = 0; m < 8; m++)
            #pragma unroll
            for (int n = 0; n < 4; n++) acc[m][n] = (float4v){0.f,0.f,0.f,0.f};
        #pragma unroll
        for (int c = 0; c < 2; c++){
            short8 ah[8], al[8];
            #pragma unroll
            for (int m = 0; m < 8; m++){
                ah[m] = *(const short8*)(whi + (m*16 + l)*64 + c*32 + q*8);
                al[m] = *(const short8*)(wlo + (m*16 + l)*64 + c*32 + q*8);
            }
            #pragma unroll
            for (int n = 0; n < 4; n++){
                short8 bh = *(const short8*)(&Xhi[(pb + n*16 + l)*72 + c*32 + q*8]);
                short8 bl = *(const short8*)(&Xlo[(pb + n*16 + l)*72 + c*32 + q*8]);
                #pragma unroll
                for (int m = 0; m < 8; m++){
                    acc[m][n] = __builtin_amdgcn_mfma_f32_16x16x32_bf16(ah[m], bh, acc[m][n], 0, 0, 0);
                    acc[m][n] = __builtin_amdgcn_mfma_f32_16x16x32_bf16(ah[m], bl, acc[m][n], 0, 0, 0);
                    acc[m][n] = __builtin_amdgcn_mfma_f32_16x16x32_bf16(al[m], bh, acc[m][n], 0, 0, 0);
                }
            }
        }
        #pragma unroll
        for (int m = 0; m < 8; m++){
            #pragma unroll
            for (int n = 0; n < 4; n++){
                int px = pos0 + pb + n*16 + l;
                #pragma unroll
                for (int i = 0; i < 4; i++){
                    int oc = m*16 + q*4 + i;
                    float val = acc[m][n][i];
                    if (m < 4) kpre[(size_t)(b*64 + oc)*HW + px] = val;
                    else       vpre[(size_t)(b*64 + (oc-64))*HW + px] = val;
                }
            }
        }
    }
    barrier_lds();   // stores keep draining in background

    // ---- P3: LN3(x) -> Xhi/Xlo ----
    {
        float v[64];
        float s = 0.f, ss = 0.f;
        #pragma unroll
        for (int c = 0; c < 64; c++){ float r = x[base + (size_t)c*HW]; v[c] = r; s += r; ss += r*r; }
        float mu  = s * (1.0f/64.0f);
        float var = ss * (1.0f/64.0f) - mu*mu;
        float inv = rsqrtf(var + 1e-5f);
        #pragma unroll
        for (int c0 = 0; c0 < 64; c0 += 8){
            unsigned short h8[8], l8[8];
            #pragma unroll
            for (int i = 0; i < 8; i++){
                float f = (v[c0+i]-mu)*inv*s_ln[2][c0+i] + s_ln[3][c0+i];
                unsigned short h = f2bf(f);
                h8[i] = h; l8[i] = f2bf(f - bf2f(h));
            }
            *(short8*)(&Xhi[t*72 + c0]) = *(short8*)h8;
            *(short8*)(&Xlo[t*72 + c0]) = *(short8*)l8;
        }
    }
    barrier_lds();

    // ---- P4: q GEMM: 64 oc x 64 px per wave (weight rows 128..191) ----
    {
        float4v acc[4][4];
        #pragma unroll
        for (int m = 0; m < 4; m++)
            #pragma unroll
            for (int n = 0; n < 4; n++) acc[m][n] = (float4v){0.f,0.f,0.f,0.f};
        #pragma unroll
        for (int c = 0; c < 2; c++){
            short8 ah[4], al[4];
            #pragma unroll
            for (int m = 0; m < 4; m++){
                ah[m] = *(const short8*)(whi + (128 + m*16 + l)*64 + c*32 + q*8);
                al[m] = *(const short8*)(wlo + (128 + m*16 + l)*64 + c*32 + q*8);
            }
            #pragma unroll
            for (int n = 0; n < 4; n++){
                short8 bh = *(const short8*)(&Xhi[(pb + n*16 + l)*72 + c*32 + q*8]);
                short8 bl = *(const short8*)(&Xlo[(pb + n*16 + l)*72 + c*32 + q*8]);
                #pragma unroll
                for (int m = 0; m < 4; m++){
                    acc[m][n] = __builtin_amdgcn_mfma_f32_16x16x32_bf16(ah[m], bh, acc[m][n], 0, 0, 0);
                    acc[m][n] = __builtin_amdgcn_mfma_f32_16x16x32_bf16(ah[m], bl, acc[m][n], 0, 0, 0);
                    acc[m][n] = __builtin_amdgcn_mfma_f32_16x16x32_bf16(al[m], bh, acc[m][n], 0, 0, 0);
                }
            }
        }
        #pragma unroll
        for (int m = 0; m < 4; m++){
            #pragma unroll
            for (int n = 0; n < 4; n++){
                int px = pos0 + pb + n*16 + l;
                #pragma unroll
                for (int i = 0; i < 4; i++){
                    int oc = m*16 + q*4 + i;
                    qpre[(size_t)(b*64 + oc)*HW + px] = acc[m][n][i];
                }
            }
        }
    }
}

// ---------------------------------------------------------------------------
// K2: depthwise 3x3, pad 1 (fp32 NCHW). Vectorized: 128-px tiles, each
// thread computes 4 px with float4 store.
// ---------------------------------------------------------------------------
__global__ __launch_bounds__(256) void k_dw3x3(
    const float* __restrict__ in, const float* __restrict__ w9,
    float* __restrict__ out)
{
    __shared__ float s_in[10*132];
    int t  = threadIdx.x;
    int b  = blockIdx.z >> 6, ch = blockIdx.z & 63;
    int x0 = blockIdx.x * 128, y0 = blockIdx.y * 8;
    const float* src = in + (size_t)(b*64+ch)*HW;
    for (int j = t; j < 1300; j += 256){
        int r = j / 130, cc = j - r*130;
        int gy = y0 - 1 + r, gx = x0 - 1 + cc;
        float val = 0.f;
        if (gy >= 0 && gy < 256 && gx >= 0 && gx < 256) val = src[gy*256 + gx];
        s_in[r*132 + cc] = val;
    }
    float w[9];
    #pragma unroll
    for (int k = 0; k < 9; k++) w[k] = w9[ch*9 + k];
    __syncthreads();
    int ty = t >> 5, tx4 = (t & 31) << 2;
    float o[4] = {0.f, 0.f, 0.f, 0.f};
    #pragma unroll
    for (int ky = 0; ky < 3; ky++){
        float f[6];
        #pragma unroll
        for (int i = 0; i < 6; i++) f[i] = s_in[(ty+ky)*132 + tx4 + i];
        #pragma unroll
        for (int px = 0; px < 4; px++){
            o[px] += w[ky*3+0] * f[px];
            o[px] += w[ky*3+1] * f[px+1];
            o[px] += w[ky*3+2] * f[px+2];
        }
    }
    *(float4v*)(&out[(size_t)(b*64+ch)*HW + (y0+ty)*256 + x0 + tx4]) = *(float4v*)o;
}

// ---------------------------------------------------------------------------
// K3: q.kT dots via MFMA (hi/lo bf16 3-term) + fused per-channel sum-sq.
// No LDS; frags straight from global. (R7 verified.)
// ---------------------------------------------------------------------------
__global__ __launch_bounds__(256) void k_qk_mfma(
    const float* __restrict__ q, const float* __restrict__ k,
    float* __restrict__ dots, float* __restrict__ sqq, float* __restrict__ sqk)
{
    int t = threadIdx.x;
    int b = blockIdx.x >> 8;
    int p0 = (blockIdx.x & 255) * 256;
    int wave = t >> 6, lane = t & 63;
    int h = wave;
    int row = lane & 15, kg = lane >> 4;

    const float* qrow = q + (size_t)(b*64 + h*16 + row)*HW;
    const float* krow = k + (size_t)(b*64 + h*16 + row)*HW;

    float4v acc = (float4v){0.f, 0.f, 0.f, 0.f};
    float sq = 0.f, sk = 0.f;

    for (int step = 0; step < 8; step++){
        int p = p0 + step*32 + kg*8;
        float qa[8], ka[8];
        #pragma unroll
        for (int j = 0; j < 8; j++){ qa[j] = qrow[p+j]; ka[j] = krow[p+j]; }
        unsigned short qh8[8], ql8[8], kh8[8], kl8[8];
        #pragma unroll
        for (int j = 0; j < 8; j++){
            sq += qa[j]*qa[j];
            sk += ka[j]*ka[j];
            unsigned short hh = f2bf(qa[j]);
            qh8[j] = hh; ql8[j] = f2bf(qa[j] - bf2f(hh));
            hh = f2bf(ka[j]);
            kh8[j] = hh; kl8[j] = f2bf(ka[j] - bf2f(hh));
        }
        short8 ah = *(short8*)qh8, al = *(short8*)ql8;
        short8 bh = *(short8*)kh8, bl = *(short8*)kl8;
        acc = __builtin_amdgcn_mfma_f32_16x16x32_bf16(ah, bh, acc, 0, 0, 0);
        acc = __builtin_amdgcn_mfma_f32_16x16x32_bf16(ah, bl, acc, 0, 0, 0);
        acc = __builtin_amdgcn_mfma_f32_16x16x32_bf16(al, bh, acc, 0, 0, 0);
    }

    // sum-sq reduce across kg groups (lanes row, row+16, row+32, row+48)
    sq += __shfl_xor(sq, 16); sq += __shfl_xor(sq, 32);
    sk += __shfl_xor(sk, 16); sk += __shfl_xor(sk, 32);
    if (lane < 16){
        atomicAdd(&sqq[b*64 + h*16 + row], sq);
        atomicAdd(&sqk[b*64 + h*16 + row], sk);
    }
    // C layout: cq = kg*4 + i, cd = row
    int dbase = ((b*4 + h)*16 + kg*4)*16 + row;
    atomicAdd(&dots[dbase + 0*16], acc[0]);
    atomicAdd(&dots[dbase + 1*16], acc[1]);
    atomicAdd(&dots[dbase + 2*16], acc[2]);
    atomicAdd(&dots[dbase + 3*16], acc[3]);
}

// ---------------------------------------------------------------------------
// K4: normalize + temperature + softmax over d, then fold the projection:
// M_b = Wproj @ blockdiag(A_b)  ->  x1 = x + M_b . v  (single GEMM later).
// ---------------------------------------------------------------------------
__global__ __launch_bounds__(256) void k_softmax_m(
    const float* __restrict__ dots, const float* __restrict__ sqq,
    const float* __restrict__ sqk, const float* __restrict__ temp,
    const float* __restrict__ wproj,
    unsigned short* __restrict__ Mhi, unsigned short* __restrict__ Mlo)
{
    __shared__ float s_wp[4096];
    __shared__ float s_at[1024];
    int t = threadIdx.x;
    int b = blockIdx.x;

    for (int j = t; j < 4096; j += 256) s_wp[j] = wproj[j];

    if (t < 64){
        int h = t >> 4, cq = t & 15;
        float nq = fmaxf(sqrtf(sqq[b*64 + h*16 + cq]), 1e-12f);
        float tp = temp[h];
        float l[16];
        float m = -1e30f;
        #pragma unroll
        for (int d = 0; d < 16; d++){
            float nk = fmaxf(sqrtf(sqk[b*64 + h*16 + d]), 1e-12f);
            float v = dots[((b*4+h)*16 + cq)*16 + d] / (nq*nk) * tp;
            l[d] = v; m = fmaxf(m, v);
        }
        float s = 0.f;
        #pragma unroll
        for (int d = 0; d < 16; d++){ l[d] = __expf(l[d]-m); s += l[d]; }
        float invs = 1.0f / s;
        #pragma unroll
        for (int d = 0; d < 16; d++) s_at[(h*16 + cq)*16 + d] = l[d]*invs;
    }
    __syncthreads();

    // M: 4096 entries, 16 each
    for (int e = t; e < 4096; e += 256){
        int c = e >> 6, kk = e & 63;
        int h = kk >> 4, d = kk & 15;
        float a = 0.f;
        #pragma unroll
        for (int r = 0; r < 16; r++)
            a += s_wp[c*64 + h*16 + r] * s_at[(h*16 + r)*16 + d];
        unsigned short hh = f2bf(a);
        Mhi[b*4096 + e] = hh;
        Mlo[b*4096 + e] = f2bf(a - bf2f(hh));
    }
}

// ---------------------------------------------------------------------------
// K5: x1 = x + M_b.v  (MFMA, hi/lo bf16 3-term) ; y = LN2(x1).
// Emit x1 and y as bf16 NHWC [b][y][x][c] for the MFMA SFM convs.
// ---------------------------------------------------------------------------
__global__ __launch_bounds__(256, 2) void k_attnv_mfma(
    const float* __restrict__ v, const float* __restrict__ x,
    const unsigned short* __restrict__ Mhi_g, const unsigned short* __restrict__ Mlo_g,
    const float* __restrict__ ln2w, const float* __restrict__ ln2b,
    unsigned short* __restrict__ x1_bf, unsigned short* __restrict__ y_bf)
{
    __shared__ unsigned short Mhi[64*72];    // 9216 B
    __shared__ unsigned short Mlo[64*72];    // 9216 B
    __shared__ float s_lw[64], s_lb[64];
    int t = threadIdx.x;
    int b = blockIdx.x >> 8;
    int pos0 = (blockIdx.x & 255) << 8;

    for (int e = t; e < 4096; e += 256){
        int row = e >> 6, ic = e & 63;
        Mhi[row*72 + ic] = Mhi_g[b*4096 + e];
        Mlo[row*72 + ic] = Mlo_g[b*4096 + e];
    }
    if (t < 64){ s_lw[t] = ln2w[t]; s_lb[t] = ln2b[t]; }
    __syncthreads();

    int wave = t >> 6, lane = t & 63;
    int q = lane >> 4, l = lane & 15;
    int px0 = pos0 + wave*64;                // wave's 64-px slab

    float4v acc[4][4];
    #pragma unroll
    for (int m = 0; m < 4; m++)
        #pragma unroll
        for (int n = 0; n < 4; n++) acc[m][n] = (float4v){0.f,0.f,0.f,0.f};

    #pragma unroll
    for (int c = 0; c < 2; c++){
        short8 ah[4], al[4];
        #pragma unroll
        for (int m = 0; m < 4; m++){
            ah[m] = *(const short8*)(&Mhi[(m*16 + l)*72 + c*32 + q*8]);
            al[m] = *(const short8*)(&Mlo[(m*16 + l)*72 + c*32 + q*8]);
        }
        #pragma unroll
        for (int n = 0; n < 4; n++){
            float vv[8];
            #pragma unroll
            for (int j = 0; j < 8; j++)
                vv[j] = v[(size_t)(b*64 + c*32 + q*8 + j)*HW + px0 + n*16 + l];
            unsigned short bh8[8], bl8[8];
            #pragma unroll
            for (int j = 0; j < 8; j++){
                unsigned short h = f2bf(vv[j]);
                bh8[j] = h; bl8[j] = f2bf(vv[j] - bf2f(h));
            }
            short8 bh = *(short8*)bh8, bl = *(short8*)bl8;
            #pragma unroll
            for (int m = 0; m < 4; m++){
                acc[m][n] = __builtin_amdgcn_mfma_f32_16x16x32_bf16(ah[m], bh, acc[m][n], 0, 0, 0);
                acc[m][n] = __builtin_amdgcn_mfma_f32_16x16x32_bf16(ah[m], bl, acc[m][n], 0, 0, 0);
                acc[m][n] = __builtin_amdgcn_mfma_f32_16x16x32_bf16(al[m], bh, acc[m][n], 0, 0, 0);
            }
        }
    }

    // epilogue: per n-tile -> x-add, LN2 stats via shfl over q, pack bf16
    #pragma unroll
    for (int n = 0; n < 4; n++){
        int px = px0 + n*16 + l;
        float val[4][4];
        float sn = 0.f, ssn = 0.f;
        #pragma unroll
        for (int m = 0; m < 4; m++){
            #pragma unroll
            for (int i = 0; i < 4; i++){
                float f = acc[m][n][i] + x[(size_t)(b*64 + m*16 + q*4 + i)*HW + px];
                val[m][i] = f; sn += f; ssn += f*f;
            }
        }
        sn  += __shfl_xor(sn, 16);  sn  += __shfl_xor(sn, 32);
        ssn += __shfl_xor(ssn, 16); ssn += __shfl_xor(ssn, 32);
        float mu  = sn * (1.0f/64.0f);
        float var = ssn * (1.0f/64.0f) - mu*mu;
        float inv = rsqrtf(var + 1e-5f);
        size_t nb = ((size_t)b*HW + px) * 64;
        #pragma unroll
        for (int m = 0; m < 4; m++){
            int ocb = m*16 + q*4;
            unsigned short xv[4], yv[4];
            #pragma unroll
            for (int i = 0; i < 4; i++){
                float f = val[m][i];
                xv[i] = f2bf(f);
                yv[i] = f2bf((f - mu) * inv * s_lw[ocb+i] + s_lb[ocb+i]);
            }
            *(unsigned long long*)(x1_bf + nb + ocb) = *(unsigned long long*)xv;
            *(unsigned long long*)(y_bf  + nb + ocb) = *(unsigned long long*)yv;
        }
    }
}

// ---------------------------------------------------------------------------
// Conv staging helpers: global->reg issue and reg->LDS write (T14 split).
// Geometry: 4 rows x 130 px x 32 ic (2080 short8 pieces / 256 threads).
// ---------------------------------------------------------------------------
__device__ __forceinline__ void conv_issue_loads(
    const unsigned short* __restrict__ src, int b, int y0, int x0, int c,
    int tid, short8* pf)
{
    #pragma unroll
    for (int u = 0; u < 9; u++){
        int j = u*256 + tid;
        if (j < 2080){
            int row = j / 520;
            int rem = j - row*520;
            int px  = rem >> 2;
            int part= rem & 3;
            int gy = y0 - 1 + row, gx = x0 - 1 + px;
            short8 v = (short8)0;
            if (gy >= 0 && gy < 256 && gx >= 0 && gx < 256)
                v = *(const short8*)(src + (((size_t)b*HW + gy*256 + gx) * 64) + c*32 + part*8);
            pf[u] = v;
        }
    }
}
__device__ __forceinline__ void conv_write_lds(
    unsigned short* Xs, int tid, const short8* pf)
{
    #pragma unroll
    for (int u = 0; u < 9; u++){
        int j = u*256 + tid;
        if (j < 2080){
            int row = j / 520;
            int rem = j - row*520;
            int px  = rem >> 2;
            int part= rem & 3;
            *(short8*)(&Xs[(row*130 + px)*40 + part*8]) = pf[u];
        }
    }
}

// ---------------------------------------------------------------------------
// K6a: fused dual 3x3 conv over y: t1 = gelu(conv(y,wA)), t2 = gelu(conv(y,wB)).
// Double-buffered Ws LDS (R9 verified). barrier_lds only (no vmcnt drains).
// No reg-prefetch here: 128 VGPR + 128 AGPR already at the 256 budget.
// ---------------------------------------------------------------------------
__global__ __launch_bounds__(256, 2) void k_conv_dual(
    const unsigned short* __restrict__ in,
    const unsigned short* __restrict__ wtA,
    const unsigned short* __restrict__ wtB,
    unsigned short* __restrict__ o1,
    unsigned short* __restrict__ o2)
{
    __shared__ unsigned short Xs[4*130*40];   // 41600 B
    __shared__ unsigned short WsA[2][64*40];  // 10240 B
    __shared__ unsigned short WsB[2][64*40];  // 10240 B
    int tid  = threadIdx.x;
    int b    = blockIdx.z;
    int y0   = blockIdx.y * 2;
    int x0   = blockIdx.x * 128;
    int wave = tid >> 6, lane = tid & 63;
    int q = lane >> 4, l = lane & 15;
    int r = wave >> 1;
    int pb = (wave & 1) * 64;

    float4v accA[4][4], accB[4][4];
    #pragma unroll
    for (int m = 0; m < 4; m++)
        #pragma unroll
        for (int n = 0; n < 4; n++){
            accA[m][n] = (float4v){0.f,0.f,0.f,0.f};
            accB[m][n] = (float4v){0.f,0.f,0.f,0.f};
        }

    for (int c = 0; c < 2; ++c){
        barrier_lds();
        for (int j = tid; j < 2080; j += 256){
            int row = j / 520;
            int rem = j - row*520;
            int px  = rem >> 2;
            int part= rem & 3;
            int gy = y0 - 1 + row, gx = x0 - 1 + px;
            short8 v = (short8)0;
            if (gy >= 0 && gy < 256 && gx >= 0 && gx < 256){
                v = *(const short8*)(in + (((size_t)b*HW + gy*256 + gx) * 64) + c*32 + part*8);
            }
            *(short8*)(&Xs[(row*130 + px)*40 + part*8]) = v;
        }
        {
            int oc = tid >> 2, part = tid & 3;
            *(short8*)(&WsA[0][oc*40 + part*8]) =
                *(const short8*)(wtA + ((size_t)(0*64 + oc))*64 + c*32 + part*8);
            *(short8*)(&WsB[0][oc*40 + part*8]) =
                *(const short8*)(wtB + ((size_t)(0*64 + oc))*64 + c*32 + part*8);
        }
        for (int t = 0; t < 9; ++t){
            barrier_lds();
            if (t < 8){
                int oc = tid >> 2, part = tid & 3;
                *(short8*)(&WsA[(t+1)&1][oc*40 + part*8]) =
                    *(const short8*)(wtA + ((size_t)((t+1)*64 + oc))*64 + c*32 + part*8);
                *(short8*)(&WsB[(t+1)&1][oc*40 + part*8]) =
                    *(const short8*)(wtB + ((size_t)((t+1)*64 + oc))*64 + c*32 + part*8);
            }
            int ky = t / 3, kx = t - ky*3;
            const unsigned short* wa = &WsA[t & 1][0];
            const unsigned short* wb = &WsB[t & 1][0];
            short8 afrA[4], afrB[4];
            #pragma unroll
            for (int m = 0; m < 4; m++){
                afrA[m] = *(const short8*)(wa + (m*16 + l)*40 + q*8);
                afrB[m] = *(const short8*)(wb + (m*16 + l)*40 + q*8);
            }
            #pragma unroll
            for (int n = 0; n < 4; n++){
                int px = pb + n*16 + l;
                short8 bfr = *(const short8*)(&Xs[((r+ky)*130 + px + kx)*40 + q*8]);
                #pragma unroll
                for (int m = 0; m < 4; m++){
                    accA[m][n] = __builtin_amdgcn_mfma_f32_16x16x32_bf16(afrA[m], bfr, accA[m][n], 0, 0, 0);
                    accB[m][n] = __builtin_amdgcn_mfma_f32_16x16x32_bf16(afrB[m], bfr, accB[m][n], 0, 0, 0);
                }
            }
        }
    }

    int gy = y0 + r;
    #pragma unroll
    for (int n = 0; n < 4; n++){
        int gx = x0 + pb + n*16 + l;
        size_t pixbase = ((size_t)b*HW + gy*256 + gx) * 64;
        #pragma unroll
        for (int m = 0; m < 4; m++){
            int ocb = m*16 + q*4;
            unsigned short p1[4], p2[4];
            #pragma unroll
            for (int i = 0; i < 4; i++){
                p1[i] = f2bf(gelu_exact(accA[m][n][i]));
                p2[i] = f2bf(gelu_exact(accB[m][n][i]));
            }
            *(unsigned long long*)(o1 + pixbase + ocb) = *(unsigned long long*)p1;
            *(unsigned long long*)(o2 + pixbase + ocb) = *(unsigned long long*)p2;
        }
    }
}

// ---------------------------------------------------------------------------
// K6b: fused z kernel: z = y * sigmoid(conv(t2,wB)) + conv(t1,wA).
// T14 async-STAGE: next phase's X loads issued into registers during the
// current phase's 9-tap MFMA loop; barrier_lds keeps them in flight across
// barriers. 212->248 total regs: stays at 2 waves/SIMD.
// ---------------------------------------------------------------------------
__global__ __launch_bounds__(256, 2) void k_conv_zfuse(
    const unsigned short* __restrict__ in1,   // t1
    const unsigned short* __restrict__ in2,   // t2
    const unsigned short* __restrict__ wtA,   // wadd2
    const unsigned short* __restrict__ wtB,   // wmul1
    const unsigned short* __restrict__ yb,    // y_bf
    unsigned short* __restrict__ zo)
{
    __shared__ unsigned short Xs[4*130*40];   // 41600 B
    __shared__ unsigned short Ws[2][64*40];   // 10240 B
    int tid  = threadIdx.x;
    int b    = blockIdx.z;
    int y0   = blockIdx.y * 2;
    int x0   = blockIdx.x * 128;
    int wave = tid >> 6, lane = tid & 63;
    int q = lane >> 4, l = lane & 15;
    int r = wave >> 1;
    int pb = (wave & 1) * 64;

    float4v accA[4][4], accB[4][4];
    #pragma unroll
    for (int m = 0; m < 4; m++)
        #pragma unroll
        for (int n = 0; n < 4; n++){
            accA[m][n] = (float4v){0.f,0.f,0.f,0.f};
            accB[m][n] = (float4v){0.f,0.f,0.f,0.f};
        }

    short8 pf[9];
    conv_issue_loads(in1, b, y0, x0, 0, tid, pf);

    #pragma unroll
    for (int ph = 0; ph < 4; ++ph){
        const int c    = ph >> 1;
        const int pass = ph & 1;
        const unsigned short* wt = (pass == 0) ? wtA : wtB;
        barrier_lds();                      // prev compute done reading Xs
        conv_write_lds(Xs, tid, pf);
        {
            int oc = tid >> 2, part = tid & 3;
            *(short8*)(&Ws[0][oc*40 + part*8]) =
                *(const short8*)(wt + ((size_t)oc)*64 + c*32 + part*8);
        }
        if (ph < 3){                        // prefetch next phase (hides under taps)
            const unsigned short* nsrc = ((ph+1) & 1) ? in2 : in1;
            conv_issue_loads(nsrc, b, y0, x0, (ph+1) >> 1, tid, pf);
        }
        for (int t = 0; t < 9; ++t){
            barrier_lds();
            if (t < 8){
                int oc = tid >> 2, part = tid & 3;
                *(short8*)(&Ws[(t+1)&1][oc*40 + part*8]) =
                    *(const short8*)(wt + ((size_t)((t+1)*64 + oc))*64 + c*32 + part*8);
            }
            int ky = t / 3, kx = t - ky*3;
            const unsigned short* wb = &Ws[t & 1][0];
            short8 afr[4];
            #pragma unroll
            for (int m = 0; m < 4; m++)
                afr[m] = *(const short8*)(wb + (m*16 + l)*40 + q*8);
            #pragma unroll
            for (int n = 0; n < 4; n++){
                int px = pb + n*16 + l;
                short8 bfr = *(const short8*)(&Xs[((r+ky)*130 + px + kx)*40 + q*8]);
                #pragma unroll
                for (int m = 0; m < 4; m++){
                    if (pass == 0)
                        accA[m][n] = __builtin_amdgcn_mfma_f32_16x16x32_bf16(afr[m], bfr, accA[m][n], 0, 0, 0);
                    else
                        accB[m][n] = __builtin_amdgcn_mfma_f32_16x16x32_bf16(afr[m], bfr, accB[m][n], 0, 0, 0);
                }
            }
        }
    }

    int gy = y0 + r;
    #pragma unroll
    for (int n = 0; n < 4; n++){
        int gx = x0 + pb + n*16 + l;
        size_t pixbase = ((size_t)b*HW + gy*256 + gx) * 64;
        #pragma unroll
        for (int m = 0; m < 4; m++){
            int ocb = m*16 + q*4;
            unsigned long long yu = *(const unsigned long long*)(yb + pixbase + ocb);
            const unsigned short* y4 = (const unsigned short*)&yu;
            unsigned short pk[4];
            #pragma unroll
            for (int i = 0; i < 4; i++){
                float z = bf2f(y4[i]) * sigmoid_(accB[m][n][i]) + accA[m][n][i];
                pk[i] = f2bf(z);
            }
            *(unsigned long long*)(zo + pixbase + ocb) = *(unsigned long long*)pk;
        }
    }
}

// ---------------------------------------------------------------------------
// K6c: final conv: out = x1 + conv(z, wfuse)  (fp32 NCHW out).
// R9 structure + barrier_lds (keeps 3-block occupancy; no reg-prefetch to
// avoid crossing the 170-reg 3-waves/SIMD boundary).
// ---------------------------------------------------------------------------
__global__ __launch_bounds__(256, 3) void k_conv_final(
    const unsigned short* __restrict__ in,    // z_bf
    const unsigned short* __restrict__ wt,    // wfuse taps
    const unsigned short* __restrict__ x1,    // x1_bf
    float* __restrict__ outf)
{
    __shared__ unsigned short Xs[4*130*40];   // 41600 B
    __shared__ unsigned short Ws[2][64*40];   // 10240 B
    int tid  = threadIdx.x;
    int b    = blockIdx.z;
    int y0   = blockIdx.y * 2;
    int x0   = blockIdx.x * 128;
    int wave = tid >> 6, lane = tid & 63;
    int q = lane >> 4, l = lane & 15;
    int r = wave >> 1;
    int pb = (wave & 1) * 64;

    float4v acc[4][4];
    #pragma unroll
    for (int m = 0; m < 4; m++)
        #pragma unroll
        for (int n = 0; n < 4; n++) acc[m][n] = (float4v){0.f,0.f,0.f,0.f};

    for (int c = 0; c < 2; ++c){
        barrier_lds();
        for (int j = tid; j < 2080; j += 256){
            int row = j / 520;
            int rem = j - row*520;
            int px  = rem >> 2;
            int part= rem & 3;
            int gy = y0 - 1 + row, gx = x0 - 1 + px;
            short8 v = (short8)0;
            if (gy >= 0 && gy < 256 && gx >= 0 && gx < 256){
                v = *(const short8*)(in + (((size_t)b*HW + gy*256 + gx) * 64) + c*32 + part*8);
            }
            *(short8*)(&Xs[(row*130 + px)*40 + part*8]) = v;
        }
        {
            int oc = tid >> 2, part = tid & 3;
            *(short8*)(&Ws[0][oc*40 + part*8]) =
                *(const short8*)(wt + ((size_t)(0*64 + oc))*64 + c*32 + part*8);
        }
        for (int t = 0; t < 9; ++t){
            barrier_lds();
            if (t < 8){
                int oc = tid >> 2, part = tid & 3;
                *(short8*)(&Ws[(t+1)&1][oc*40 + part*8]) =
                    *(const short8*)(wt + ((size_t)((t+1)*64 + oc))*64 + c*32 + part*8);
            }
            int ky = t / 3, kx = t - ky*3;
            const unsigned short* wb = &Ws[t & 1][0];
            short8 afr[4];
            #pragma unroll
            for (int m = 0; m < 4; m++)
                afr[m] = *(const short8*)(wb + (m*16 + l)*40 + q*8);
            #pragma unroll
            for (int n = 0; n < 4; n++){
                int px = pb + n*16 + l;
                short8 bfr = *(const short8*)(&Xs[((r+ky)*130 + px + kx)*40 + q*8]);
                #pragma unroll
                for (int m = 0; m < 4; m++)
                    acc[m][n] = __builtin_amdgcn_mfma_f32_16x16x32_bf16(afr[m], bfr, acc[m][n], 0, 0, 0);
            }
        }
    }

    int gy = y0 + r;
    #pragma unroll
    for (int n = 0; n < 4; n++){
        int gx = x0 + pb + n*16 + l;
        size_t pixbase = ((size_t)b*HW + gy*256 + gx) * 64;
        #pragma unroll
        for (int m = 0; m < 4; m++){
            int ocb = m*16 + q*4;
            unsigned long long xu = *(const unsigned long long*)(x1 + pixbase + ocb);
            const unsigned short* x14 = (const unsigned short*)&xu;
            #pragma unroll
            for (int i = 0; i < 4; i++){
                outf[((size_t)(b*64 + ocb + i))*HW + gy*256 + gx] = bf2f(x14[i]) + acc[m][n][i];
            }
        }
    }
}

// ---------------------------------------------------------------------------
extern "C" void kernel_launch(void* const* d_in, const int* in_sizes, int n_in,
                              void* d_out, int out_size, void* d_ws, size_t ws_size,
                              hipStream_t stream)
{
    const float* x     = (const float*)d_in[0];
    const float* ref   = (const float*)d_in[1];
    const float* ln1w  = (const float*)d_in[2];
    const float* ln1b  = (const float*)d_in[3];
    const float* ln2w  = (const float*)d_in[4];
    const float* ln2b  = (const float*)d_in[5];
    const float* ln3w  = (const float*)d_in[6];
    const float* ln3b  = (const float*)d_in[7];
    const float* wkv   = (const float*)d_in[8];
    const float* wkvdw = (const float*)d_in[9];
    const float* wq    = (const float*)d_in[10];
    const float* wqdw  = (const float*)d_in[11];
    const float* wproj = (const float*)d_in[12];
    const float* temp  = (const float*)d_in[13];
    const float* wadd1 = (const float*)d_in[14];
    const float* wadd2 = (const float*)d_in[15];
    const float* wmul1 = (const float*)d_in[16];
    const float* wfuse = (const float*)d_in[17];
    float* out = (float*)d_out;

    const size_t S = (size_t)4 * 64 * HW;   // 16,777,216 elements per tensor
    float* ws = (float*)d_ws;
    float* b0   = ws;            // kpre -> v ; then z_bf (bf16)
    float* b1   = ws + S;        // vpre ; then y_bf | x1_bf (bf16 halves)
    float* b2   = ws + 2*S;      // qpre -> k ; then t1_bf | t2_bf (bf16 halves)
    float* dots = ws + 3*S;      // 4096
    float* sqq  = dots + 4096;   // 256
    float* sqk  = sqq + 256;     // 256
    float* attn = sqk + 256;     // 4096 (unused, layout stability)
    unsigned short* Wt   = (unsigned short*)(attn + 4096);  // 4*36864 bf16
    unsigned short* Mhi  = Wt + 4*36864;                    // 4*4096 bf16
    unsigned short* Mlo  = Mhi + 4*4096;                    // 4*4096 bf16
    unsigned short* WHhi = Mlo + 4*4096;                    // 12288 bf16
    unsigned short* WHlo = WHhi + 12288;                    // 12288 bf16
    if (ws_size < 3*S*4 + 8704*4 + (4*36864 + 2*4*4096 + 2*12288)*2) return;

    unsigned short* y_bf  = (unsigned short*)b1;
    unsigned short* x1_bf = (unsigned short*)b1 + S;
    unsigned short* t1_bf = (unsigned short*)b2;
    unsigned short* t2_bf = (unsigned short*)b2 + S;
    unsigned short* z_bf  = (unsigned short*)b0;

    // weight prep (independent): 147456 SFM taps + 12288 kv/q hi/lo rows
    k_wprep<<<624, 256, 0, stream>>>(wadd1, wadd2, wmul1, wfuse, wkv, wq,
                                     Wt, WHhi, WHlo);

    // LN1/LN3 + 1x1 convs (MFMA): kpre->b0, vpre->b1, qpre->b2 (block 0 zeroes dots)
    k_ln_1x1_mfma<<<1024, 256, 0, stream>>>(x, ref, ln1w, ln1b, ln3w, ln3b,
                                            WHhi, WHlo, b0, b1, b2, dots);
    // depthwise 3x3: q (b2->out), k (b0->b2), v (b1->b0)
    dim3 gdw(2, 32, 256);
    k_dw3x3<<<gdw, 256, 0, stream>>>(b2, wqdw,         out);
    k_dw3x3<<<gdw, 256, 0, stream>>>(b0, wkvdw,        b2);
    k_dw3x3<<<gdw, 256, 0, stream>>>(b1, wkvdw + 64*9, b0);

    // q.kT dots + sum-sq via MFMA (q in out, k in b2)
    k_qk_mfma<<<1024, 256, 0, stream>>>(out, b2, dots, sqq, sqk);
    // softmax + fold proj into per-batch M = wproj @ blockdiag(A)
    k_softmax_m<<<4, 256, 0, stream>>>(dots, sqq, sqk, temp, wproj, Mhi, Mlo);

    // x1 = x + M.v (MFMA) ; y = LN2(x1) -> bf16 NHWC
    k_attnv_mfma<<<1024, 256, 0, stream>>>(b0, x, Mhi, Mlo, ln2w, ln2b,
                                           x1_bf, y_bf);

    // SFM: 3 fused MFMA conv kernels. Wt taps: [0]=wadd1 [1]=wadd2 [2]=wmul1 [3]=wfuse
    dim3 gc(2, 128, 4);
    k_conv_dual<<<gc, 256, 0, stream>>>(y_bf, Wt + 0*36864, Wt + 2*36864,
                                        t1_bf, t2_bf);                 // t1, t2
    k_conv_zfuse<<<gc, 256, 0, stream>>>(t1_bf, t2_bf, Wt + 1*36864,
                                         Wt + 2*36864, y_bf, z_bf);    // z
    k_conv_final<<<gc, 256, 0, stream>>>(z_bf, Wt + 3*36864, x1_bf, out); // out
}